// Round 4
// baseline (3261.916 us; speedup 1.0000x reference)
//
#include <hip/hip_runtime.h>
#include <math.h>

// ---------------------------------------------------------------------------
// Problem constants
// ---------------------------------------------------------------------------
#define B_SZ 8
#define L_SZ 1024
#define DM 512          // d_model
#define DFF 2048        // d_ff
#define DIN 1024        // expand * d_model
#define DSTATE 16
#define DTRANK 32
#define MROWS (B_SZ * L_SZ)   // 8192

// ---------------------------------------------------------------------------
// Tiled fp32 GEMM: C(M,N) = A(M,K) @ W(N,K)^T with epilogues.
// M = 8192; N % 64 == 0; K % 16 == 0 for all calls here.
// ---------------------------------------------------------------------------
constexpr int EPI_NONE = 0;
constexpr int EPI_BIAS_GELU = 1;  // + bias[col], exact gelu
constexpr int EPI_BIAS_RES = 2;   // + bias[col] + res[row, col]
constexpr int EPI_GATE = 3;       // C[r,c] = C[r,c] * silu(acc)

#define BM 64
#define BN 64
#define BKK 16

template <int EPI, bool FLIPA, bool ACCUM>
__global__ __launch_bounds__(256) void gemm_k(
    const float* __restrict__ A, int lda,
    const float* __restrict__ W, int ldw,
    float* __restrict__ C, int ldc,
    const float* __restrict__ bias,
    const float* __restrict__ res,
    int K) {
  __shared__ float As[BKK][BM + 4];
  __shared__ float Ws[BKK][BN + 4];
  const int tid = threadIdx.x;
  const int m0 = blockIdx.y * BM;
  const int n0 = blockIdx.x * BN;
  const int tx = tid & 15;
  const int ty = tid >> 4;
  const int lrow = tid >> 2;        // 0..63
  const int lcol = (tid & 3) * 4;   // 0,4,8,12

  int arow = m0 + lrow;
  if (FLIPA) { int t = arow & (L_SZ - 1); arow = (arow - t) + (L_SZ - 1 - t); }
  const float* Arow = A + (long)arow * lda;
  const float* Wrow = W + (long)(n0 + lrow) * ldw;

  float acc[4][4] = {};
  for (int k0 = 0; k0 < K; k0 += BKK) {
    float4 av = *(const float4*)(Arow + k0 + lcol);
    float4 wv = *(const float4*)(Wrow + k0 + lcol);
    As[lcol + 0][lrow] = av.x; As[lcol + 1][lrow] = av.y;
    As[lcol + 2][lrow] = av.z; As[lcol + 3][lrow] = av.w;
    Ws[lcol + 0][lrow] = wv.x; Ws[lcol + 1][lrow] = wv.y;
    Ws[lcol + 2][lrow] = wv.z; Ws[lcol + 3][lrow] = wv.w;
    __syncthreads();
#pragma unroll
    for (int k = 0; k < BKK; ++k) {
      float a[4], b[4];
#pragma unroll
      for (int i = 0; i < 4; ++i) a[i] = As[k][ty * 4 + i];
#pragma unroll
      for (int j = 0; j < 4; ++j) b[j] = Ws[k][tx * 4 + j];
#pragma unroll
      for (int i = 0; i < 4; ++i)
#pragma unroll
        for (int j = 0; j < 4; ++j) acc[i][j] += a[i] * b[j];
    }
    __syncthreads();
  }

#pragma unroll
  for (int i = 0; i < 4; ++i) {
    int r = m0 + ty * 4 + i;
#pragma unroll
    for (int j = 0; j < 4; ++j) {
      int c = n0 + tx * 4 + j;
      long oi = (long)r * ldc + c;
      float v = acc[i][j];
      if (EPI == EPI_BIAS_GELU) {
        v += bias[c];
        v = 0.5f * v * (1.f + erff(v * 0.70710678118654752440f));
      } else if (EPI == EPI_BIAS_RES) {
        v += bias[c] + res[oi];
      } else if (EPI == EPI_GATE) {
        float sz = v / (1.f + __expf(-v));   // silu(z)
        v = C[oi] * sz;
      }
      if constexpr (ACCUM) {
        C[oi] += v;
      } else {
        C[oi] = v;
      }
    }
  }
}

// ---------------------------------------------------------------------------
// Fused merge: newx(M,DM) = y1 @ W1^T + flip_L(y2) @ W2^T + xres.
// Composite K-loop of 2*DIN; second phase reads y2 rows L-flipped.
// ---------------------------------------------------------------------------
__global__ __launch_bounds__(256) void merge_k(
    const float* __restrict__ y1, const float* __restrict__ y2,
    const float* __restrict__ W1, const float* __restrict__ W2,
    const float* __restrict__ xres, float* __restrict__ newx) {
  __shared__ float As[BKK][BM + 4];
  __shared__ float Ws[BKK][BN + 4];
  const int tid = threadIdx.x;
  const int m0 = blockIdx.y * BM;
  const int n0 = blockIdx.x * BN;
  const int tx = tid & 15;
  const int ty = tid >> 4;
  const int lrow = tid >> 2;
  const int lcol = (tid & 3) * 4;

  int r1 = m0 + lrow;
  int t = r1 & (L_SZ - 1);
  int r2 = (r1 - t) + (L_SZ - 1 - t);
  const float* A1 = y1 + (long)r1 * DIN;
  const float* A2 = y2 + (long)r2 * DIN;
  const float* Wr1 = W1 + (long)(n0 + lrow) * DIN;
  const float* Wr2 = W2 + (long)(n0 + lrow) * DIN;

  float acc[4][4] = {};
  for (int k0 = 0; k0 < 2 * DIN; k0 += BKK) {
    const bool ph2 = (k0 >= DIN);
    const int kk = ph2 ? (k0 - DIN) : k0;
    float4 av = *(const float4*)((ph2 ? A2 : A1) + kk + lcol);
    float4 wv = *(const float4*)((ph2 ? Wr2 : Wr1) + kk + lcol);
    As[lcol + 0][lrow] = av.x; As[lcol + 1][lrow] = av.y;
    As[lcol + 2][lrow] = av.z; As[lcol + 3][lrow] = av.w;
    Ws[lcol + 0][lrow] = wv.x; Ws[lcol + 1][lrow] = wv.y;
    Ws[lcol + 2][lrow] = wv.z; Ws[lcol + 3][lrow] = wv.w;
    __syncthreads();
#pragma unroll
    for (int k = 0; k < BKK; ++k) {
      float a[4], b[4];
#pragma unroll
      for (int i = 0; i < 4; ++i) a[i] = As[k][ty * 4 + i];
#pragma unroll
      for (int j = 0; j < 4; ++j) b[j] = Ws[k][tx * 4 + j];
#pragma unroll
      for (int i = 0; i < 4; ++i)
#pragma unroll
        for (int j = 0; j < 4; ++j) acc[i][j] += a[i] * b[j];
    }
    __syncthreads();
  }

#pragma unroll
  for (int i = 0; i < 4; ++i) {
    int r = m0 + ty * 4 + i;
#pragma unroll
    for (int j = 0; j < 4; ++j) {
      int c = n0 + tx * 4 + j;
      newx[(long)r * DM + c] = acc[i][j] + xres[(long)r * DM + c];
    }
  }
}

// ---------------------------------------------------------------------------
// Depthwise causal conv (k=4) + bias + silu. xs(B,L,DIN) -> xc. fp32.
// ---------------------------------------------------------------------------
__global__ __launch_bounds__(256) void conv_silu_k(
    const float* __restrict__ xs, const float* __restrict__ w,
    const float* __restrict__ b, float* __restrict__ xc) {
  long idx = (long)blockIdx.x * 256 + threadIdx.x;
  int d = (int)(idx & (DIN - 1));
  long bt = idx >> 10;              // 0..8191
  int t = (int)(bt & (L_SZ - 1));
  long base = bt * DIN + d;
  float acc = b[d];
  if (t >= 3) acc += xs[base - 3L * DIN] * w[d * 4 + 0];
  if (t >= 2) acc += xs[base - 2L * DIN] * w[d * 4 + 1];
  if (t >= 1) acc += xs[base - 1L * DIN] * w[d * 4 + 2];
  acc += xs[base] * w[d * 4 + 3];
  xc[base] = acc / (1.f + __expf(-acc));
}

// ---------------------------------------------------------------------------
// Selective scan with FUSED dt-projection+softplus, + skip (u*D).
// One 16-lane group per (b, d); lane = state index s.
// dt[b,t,d] = softplus(dtb[d] + sum_{r<32} xdbl[b,t,r] * dtw[d,r]) computed
// via per-lane 2-element partials + 16-lane butterfly reduce.
// Output y (UNGATED) written at lane 0. Gating happens later in a GEMM epi.
// ---------------------------------------------------------------------------
__global__ __launch_bounds__(256) void scan_k(
    const float* __restrict__ u, const float* __restrict__ xdbl,
    const float* __restrict__ dtw, const float* __restrict__ dtb,
    const float* __restrict__ Alog, const float* __restrict__ Dp,
    float* __restrict__ out) {
  int tid = threadIdx.x;
  int s = tid & 15;
  int gi = tid >> 4;                  // 16 groups per block
  int blk = blockIdx.x;               // 0..511
  int b = blk >> 6;
  int d = ((blk & 63) << 4) + gi;
  float w0 = dtw[d * DTRANK + 2 * s];
  float w1 = dtw[d * DTRANK + 2 * s + 1];
  float bd = dtb[d];
  float A = -__expf(Alog[d * DSTATE + s]);
  float Dd = Dp[d];
  float h = 0.f;
  long iu = (long)b * L_SZ * DIN + d;
  long ix = (long)b * L_SZ * 64;
  for (int t = 0; t < L_SZ; ++t) {
    float x0 = xdbl[ix + 2 * s];
    float x1 = xdbl[ix + 2 * s + 1];
    float Bv = xdbl[ix + DTRANK + s];
    float Cv = xdbl[ix + DTRANK + DSTATE + s];
    float uv = u[iu];
    float pdt = x0 * w0 + x1 * w1;
    pdt += __shfl_xor(pdt, 1, 16);
    pdt += __shfl_xor(pdt, 2, 16);
    pdt += __shfl_xor(pdt, 4, 16);
    pdt += __shfl_xor(pdt, 8, 16);
    float dtv = pdt + bd;
    dtv = (dtv > 20.f) ? dtv : log1pf(__expf(dtv));   // softplus
    float da = __expf(dtv * A);
    h = da * h + (dtv * uv) * Bv;
    float p = h * Cv;
    p += __shfl_xor(p, 1, 16);
    p += __shfl_xor(p, 2, 16);
    p += __shfl_xor(p, 4, 16);
    p += __shfl_xor(p, 8, 16);
    if (s == 0) out[iu] = p + Dd * uv;
    iu += DIN;
    ix += 64;
  }
}

// ---------------------------------------------------------------------------
// LayerNorm over last dim (512). One block per row. fp32 -> fp32.
// ---------------------------------------------------------------------------
__global__ __launch_bounds__(256) void ln_k(
    const float* __restrict__ xin, const float* __restrict__ g,
    const float* __restrict__ bb, float* __restrict__ out) {
  int row = blockIdx.x;
  const float* p = xin + (long)row * DM;
  int tid = threadIdx.x;
  float x0 = p[tid], x1 = p[tid + 256];
  float sum = x0 + x1;
  float sq = x0 * x0 + x1 * x1;
#pragma unroll
  for (int o = 1; o < 64; o <<= 1) {
    sum += __shfl_xor(sum, o, 64);
    sq += __shfl_xor(sq, o, 64);
  }
  __shared__ float ssum[4], ssq[4];
  int wv = tid >> 6;
  if ((tid & 63) == 0) { ssum[wv] = sum; ssq[wv] = sq; }
  __syncthreads();
  sum = ssum[0] + ssum[1] + ssum[2] + ssum[3];
  sq = ssq[0] + ssq[1] + ssq[2] + ssq[3];
  float mean = sum * (1.f / DM);
  float var = sq * (1.f / DM) - mean * mean;
  float rstd = rsqrtf(var + 1e-5f);
  float* o = out + (long)row * DM;
  o[tid] = (x0 - mean) * rstd * g[tid] + bb[tid];
  o[tid + 256] = (x1 - mean) * rstd * g[tid + 256] + bb[tid + 256];
}

// ---------------------------------------------------------------------------
// Orchestration. fp32 everywhere. Workspace: 3 slots x 32 MB = 96 MB.
//  S0: xs1 -> xdbl1(2MB head) -> xs2 -> xdbl2(2MB head)
//      -> newx(16MB @ +0) / xln(16MB @ +16MB)
//  S1: xc1 -> y1 -> gated y1 -> ffn_half (8192x1024 f32 = 32MB)
//  S2: xc2 -> y2 -> gated y2 -> out_acc (16MB)
// ---------------------------------------------------------------------------
extern "C" void kernel_launch(void* const* d_in, const int* in_sizes, int n_in,
                              void* d_out, int out_size, void* d_ws, size_t ws_size,
                              hipStream_t stream) {
  const float* x = (const float*)d_in[0];
  const float* in1_w = (const float*)d_in[1];
  const float* conv1_w = (const float*)d_in[2];
  const float* conv1_b = (const float*)d_in[3];
  const float* xp1_w = (const float*)d_in[4];
  const float* dtp1_w = (const float*)d_in[5];
  const float* dtp1_b = (const float*)d_in[6];
  const float* Alog1 = (const float*)d_in[7];
  const float* D1 = (const float*)d_in[8];
  const float* outp1_w = (const float*)d_in[9];
  const float* in2_w = (const float*)d_in[10];
  const float* conv2_w = (const float*)d_in[11];
  const float* conv2_b = (const float*)d_in[12];
  const float* xp2_w = (const float*)d_in[13];
  const float* dtp2_w = (const float*)d_in[14];
  const float* dtp2_b = (const float*)d_in[15];
  const float* Alog2 = (const float*)d_in[16];
  const float* D2 = (const float*)d_in[17];
  const float* outp2_w = (const float*)d_in[18];
  const float* c1_w = (const float*)d_in[19];
  const float* c1_b = (const float*)d_in[20];
  const float* c2_w = (const float*)d_in[21];
  const float* c2_b = (const float*)d_in[22];
  const float* ln1_g = (const float*)d_in[23];
  const float* ln1_b = (const float*)d_in[24];
  const float* ln2_g = (const float*)d_in[25];
  const float* ln2_b = (const float*)d_in[26];

  const long SLOT = 8L * 1024 * 1024;   // 8M floats = 32 MB
  float* S0 = (float*)d_ws;
  float* S1 = S0 + SLOT;
  float* S2 = S1 + SLOT;
  float* newx = S0;                     // 4M floats
  float* xln = S0 + 4 * 1024 * 1024;    // 4M floats
  float* outacc = S2;                   // 4M floats

  dim3 blk(256);
  auto grid = [](int N) { return dim3(N / BN, MROWS / BM); };

  // ---- direction 1 ----
  gemm_k<EPI_NONE, false, false><<<grid(DIN), blk, 0, stream>>>(
      x, DM, in1_w, DM, S0, DIN, nullptr, nullptr, DM);                   // xs1
  conv_silu_k<<<(MROWS * DIN) / 256, blk, 0, stream>>>(S0, conv1_w, conv1_b, S1);
  gemm_k<EPI_NONE, false, false><<<grid(64), blk, 0, stream>>>(
      S1, DIN, xp1_w, DIN, S0, 64, nullptr, nullptr, DIN);                // xdbl1
  scan_k<<<B_SZ * (DIN / 16), blk, 0, stream>>>(S1, S0, dtp1_w, dtp1_b,
                                                Alog1, D1, S1);           // y1
  gemm_k<EPI_GATE, false, false><<<grid(DIN), blk, 0, stream>>>(
      x, DM, in1_w + (long)DIN * DM, DM, S1, DIN, nullptr, nullptr, DM);  // y1*=silu(z1)

  // ---- direction 2 (flipped sequence) ----
  gemm_k<EPI_NONE, true, false><<<grid(DIN), blk, 0, stream>>>(
      x, DM, in2_w, DM, S0, DIN, nullptr, nullptr, DM);                   // xs2
  conv_silu_k<<<(MROWS * DIN) / 256, blk, 0, stream>>>(S0, conv2_w, conv2_b, S2);
  gemm_k<EPI_NONE, false, false><<<grid(64), blk, 0, stream>>>(
      S2, DIN, xp2_w, DIN, S0, 64, nullptr, nullptr, DIN);                // xdbl2
  scan_k<<<B_SZ * (DIN / 16), blk, 0, stream>>>(S2, S0, dtp2_w, dtp2_b,
                                                Alog2, D2, S2);           // y2
  gemm_k<EPI_GATE, true, false><<<grid(DIN), blk, 0, stream>>>(
      x, DM, in2_w + (long)DIN * DM, DM, S2, DIN, nullptr, nullptr, DM);  // y2*=silu(z2)

  // ---- merge: newx = y1@W1^T + flip(y2)@W2^T + x ----
  merge_k<<<grid(DM), blk, 0, stream>>>(S1, S2, outp1_w, outp2_w, x, newx);

  // ---- LN1 ----
  ln_k<<<MROWS, blk, 0, stream>>>(newx, ln1_g, ln1_b, xln);

  // ---- FFN, chunked over DFF (2 chunks of 1024) ----
  // chunk 0
  gemm_k<EPI_BIAS_GELU, false, false><<<grid(1024), blk, 0, stream>>>(
      xln, DM, c1_w, DM, S1, 1024, c1_b, nullptr, DM);
  gemm_k<EPI_BIAS_RES, false, false><<<grid(DM), blk, 0, stream>>>(
      S1, 1024, c2_w, DFF, outacc, DM, c2_b, xln, 1024);
  // chunk 1
  gemm_k<EPI_BIAS_GELU, false, false><<<grid(1024), blk, 0, stream>>>(
      xln, DM, c1_w + 1024L * DM, DM, S1, 1024, c1_b + 1024, nullptr, DM);
  gemm_k<EPI_NONE, false, true><<<grid(DM), blk, 0, stream>>>(
      S1, 1024, c2_w + 1024, DFF, outacc, DM, nullptr, nullptr, 1024);

  // ---- LN2 -> fp32 out ----
  ln_k<<<MROWS, blk, 0, stream>>>(outacc, ln2_g, ln2_b, (float*)d_out);
}

// Round 5
// 2526.294 us; speedup vs baseline: 1.2912x; 1.2912x over previous
//
#include <hip/hip_runtime.h>
#include <math.h>

// ---------------------------------------------------------------------------
// Problem constants
// ---------------------------------------------------------------------------
#define B_SZ 8
#define L_SZ 1024
#define DM 512          // d_model
#define DFF 2048        // d_ff
#define DIN 1024        // expand * d_model
#define DSTATE 16
#define DTRANK 32
#define MROWS (B_SZ * L_SZ)   // 8192

// ---------------------------------------------------------------------------
// Tiled fp32 GEMM: C(M,N) = A(M,K) @ W(N,K)^T with epilogues.
// M = 8192; N % 64 == 0; K % 16 == 0 for all calls here.
// ---------------------------------------------------------------------------
constexpr int EPI_NONE = 0;
constexpr int EPI_BIAS_GELU = 1;      // + bias[col], exact gelu
constexpr int EPI_BIAS_RES = 2;       // + bias[col] + res[row, col]
constexpr int EPI_GATE = 3;           // C[r,c] = C[r,c] * silu(acc)
constexpr int EPI_BIAS_SOFTPLUS = 4;  // softplus(acc + bias[col])

#define BM 64
#define BN 64
#define BKK 16

template <int EPI, bool FLIPA, bool ACCUM>
__global__ __launch_bounds__(256) void gemm_k(
    const float* __restrict__ A, int lda,
    const float* __restrict__ W, int ldw,
    float* __restrict__ C, int ldc,
    const float* __restrict__ bias,
    const float* __restrict__ res,
    int K) {
  __shared__ float As[BKK][BM + 4];
  __shared__ float Ws[BKK][BN + 4];
  const int tid = threadIdx.x;
  const int m0 = blockIdx.y * BM;
  const int n0 = blockIdx.x * BN;
  const int tx = tid & 15;
  const int ty = tid >> 4;
  const int lrow = tid >> 2;        // 0..63
  const int lcol = (tid & 3) * 4;   // 0,4,8,12

  int arow = m0 + lrow;
  if (FLIPA) { int t = arow & (L_SZ - 1); arow = (arow - t) + (L_SZ - 1 - t); }
  const float* Arow = A + (long)arow * lda;
  const float* Wrow = W + (long)(n0 + lrow) * ldw;

  float acc[4][4] = {};
  for (int k0 = 0; k0 < K; k0 += BKK) {
    float4 av = *(const float4*)(Arow + k0 + lcol);
    float4 wv = *(const float4*)(Wrow + k0 + lcol);
    As[lcol + 0][lrow] = av.x; As[lcol + 1][lrow] = av.y;
    As[lcol + 2][lrow] = av.z; As[lcol + 3][lrow] = av.w;
    Ws[lcol + 0][lrow] = wv.x; Ws[lcol + 1][lrow] = wv.y;
    Ws[lcol + 2][lrow] = wv.z; Ws[lcol + 3][lrow] = wv.w;
    __syncthreads();
#pragma unroll
    for (int k = 0; k < BKK; ++k) {
      float a[4], b[4];
#pragma unroll
      for (int i = 0; i < 4; ++i) a[i] = As[k][ty * 4 + i];
#pragma unroll
      for (int j = 0; j < 4; ++j) b[j] = Ws[k][tx * 4 + j];
#pragma unroll
      for (int i = 0; i < 4; ++i)
#pragma unroll
        for (int j = 0; j < 4; ++j) acc[i][j] += a[i] * b[j];
    }
    __syncthreads();
  }

#pragma unroll
  for (int i = 0; i < 4; ++i) {
    int r = m0 + ty * 4 + i;
#pragma unroll
    for (int j = 0; j < 4; ++j) {
      int c = n0 + tx * 4 + j;
      long oi = (long)r * ldc + c;
      float v = acc[i][j];
      if (EPI == EPI_BIAS_GELU) {
        v += bias[c];
        v = 0.5f * v * (1.f + erff(v * 0.70710678118654752440f));
      } else if (EPI == EPI_BIAS_RES) {
        v += bias[c] + res[oi];
      } else if (EPI == EPI_GATE) {
        float sz = v / (1.f + __expf(-v));   // silu(z)
        v = C[oi] * sz;
      } else if (EPI == EPI_BIAS_SOFTPLUS) {
        v += bias[c];
        v = (v > 20.f) ? v : log1pf(__expf(v));
      }
      if constexpr (ACCUM) {
        C[oi] += v;
      } else {
        C[oi] = v;
      }
    }
  }
}

// ---------------------------------------------------------------------------
// Fused merge: newx(M,DM) = y1 @ W1^T + flip_L(y2) @ W2^T + xres.
// Composite K-loop of 2*DIN; second phase reads y2 rows L-flipped.
// ---------------------------------------------------------------------------
__global__ __launch_bounds__(256) void merge_k(
    const float* __restrict__ y1, const float* __restrict__ y2,
    const float* __restrict__ W1, const float* __restrict__ W2,
    const float* __restrict__ xres, float* __restrict__ newx) {
  __shared__ float As[BKK][BM + 4];
  __shared__ float Ws[BKK][BN + 4];
  const int tid = threadIdx.x;
  const int m0 = blockIdx.y * BM;
  const int n0 = blockIdx.x * BN;
  const int tx = tid & 15;
  const int ty = tid >> 4;
  const int lrow = tid >> 2;
  const int lcol = (tid & 3) * 4;

  int r1 = m0 + lrow;
  int t = r1 & (L_SZ - 1);
  int r2 = (r1 - t) + (L_SZ - 1 - t);
  const float* A1 = y1 + (long)r1 * DIN;
  const float* A2 = y2 + (long)r2 * DIN;
  const float* Wr1 = W1 + (long)(n0 + lrow) * DIN;
  const float* Wr2 = W2 + (long)(n0 + lrow) * DIN;

  float acc[4][4] = {};
  for (int k0 = 0; k0 < 2 * DIN; k0 += BKK) {
    const bool ph2 = (k0 >= DIN);
    const int kk = ph2 ? (k0 - DIN) : k0;
    float4 av = *(const float4*)((ph2 ? A2 : A1) + kk + lcol);
    float4 wv = *(const float4*)((ph2 ? Wr2 : Wr1) + kk + lcol);
    As[lcol + 0][lrow] = av.x; As[lcol + 1][lrow] = av.y;
    As[lcol + 2][lrow] = av.z; As[lcol + 3][lrow] = av.w;
    Ws[lcol + 0][lrow] = wv.x; Ws[lcol + 1][lrow] = wv.y;
    Ws[lcol + 2][lrow] = wv.z; Ws[lcol + 3][lrow] = wv.w;
    __syncthreads();
#pragma unroll
    for (int k = 0; k < BKK; ++k) {
      float a[4], b[4];
#pragma unroll
      for (int i = 0; i < 4; ++i) a[i] = As[k][ty * 4 + i];
#pragma unroll
      for (int j = 0; j < 4; ++j) b[j] = Ws[k][tx * 4 + j];
#pragma unroll
      for (int i = 0; i < 4; ++i)
#pragma unroll
        for (int j = 0; j < 4; ++j) acc[i][j] += a[i] * b[j];
    }
    __syncthreads();
  }

#pragma unroll
  for (int i = 0; i < 4; ++i) {
    int r = m0 + ty * 4 + i;
#pragma unroll
    for (int j = 0; j < 4; ++j) {
      int c = n0 + tx * 4 + j;
      newx[(long)r * DM + c] = acc[i][j] + xres[(long)r * DM + c];
    }
  }
}

// ---------------------------------------------------------------------------
// Depthwise causal conv (k=4) + bias + silu. xs(B,L,DIN) -> xc. fp32.
// ---------------------------------------------------------------------------
__global__ __launch_bounds__(256) void conv_silu_k(
    const float* __restrict__ xs, const float* __restrict__ w,
    const float* __restrict__ b, float* __restrict__ xc) {
  long idx = (long)blockIdx.x * 256 + threadIdx.x;
  int d = (int)(idx & (DIN - 1));
  long bt = idx >> 10;              // 0..8191
  int t = (int)(bt & (L_SZ - 1));
  long base = bt * DIN + d;
  float acc = b[d];
  if (t >= 3) acc += xs[base - 3L * DIN] * w[d * 4 + 0];
  if (t >= 2) acc += xs[base - 2L * DIN] * w[d * 4 + 1];
  if (t >= 1) acc += xs[base - 1L * DIN] * w[d * 4 + 2];
  acc += xs[base] * w[d * 4 + 3];
  xc[base] = acc / (1.f + __expf(-acc));
}

// ---------------------------------------------------------------------------
// Selective scan + skip (u*D). dt is precomputed (GEMM). Ungated output:
// gating applied later as a GEMM epilogue.
// One 16-lane group per (b, d); lane = state index s.
// Per lane-step: 4 loads (2 broadcast), 1 exp, 2 fma, 1 mul, 4 shuffles.
// ---------------------------------------------------------------------------
__global__ __launch_bounds__(256) void scan_k(
    const float* __restrict__ dt, const float* u,
    const float* __restrict__ xdbl,
    const float* __restrict__ Alog, const float* __restrict__ Dp,
    float* out) {
  int tid = threadIdx.x;
  int s = tid & 15;
  int gi = tid >> 4;                  // 16 groups per block
  int blk = blockIdx.x;               // 0..511
  int b = blk >> 6;
  int d = ((blk & 63) << 4) + gi;
  float A = -__expf(Alog[d * DSTATE + s]);
  float Dd = Dp[d];
  float h = 0.f;
  long iu = (long)b * L_SZ * DIN + d;
  long ix = (long)b * L_SZ * 64 + DTRANK + s;
  for (int t = 0; t < L_SZ; ++t) {
    float dtv = dt[iu];
    float uv = u[iu];
    float Bv = xdbl[ix];
    float Cv = xdbl[ix + DSTATE];
    float da = __expf(dtv * A);
    h = da * h + (dtv * uv) * Bv;
    float p = h * Cv;
    p += __shfl_xor(p, 1, 16);
    p += __shfl_xor(p, 2, 16);
    p += __shfl_xor(p, 4, 16);
    p += __shfl_xor(p, 8, 16);
    if (s == 0) out[iu] = p + Dd * uv;
    iu += DIN;
    ix += 64;
  }
}

// ---------------------------------------------------------------------------
// LayerNorm over last dim (512). One block per row. fp32 -> fp32.
// ---------------------------------------------------------------------------
__global__ __launch_bounds__(256) void ln_k(
    const float* __restrict__ xin, const float* __restrict__ g,
    const float* __restrict__ bb, float* __restrict__ out) {
  int row = blockIdx.x;
  const float* p = xin + (long)row * DM;
  int tid = threadIdx.x;
  float x0 = p[tid], x1 = p[tid + 256];
  float sum = x0 + x1;
  float sq = x0 * x0 + x1 * x1;
#pragma unroll
  for (int o = 1; o < 64; o <<= 1) {
    sum += __shfl_xor(sum, o, 64);
    sq += __shfl_xor(sq, o, 64);
  }
  __shared__ float ssum[4], ssq[4];
  int wv = tid >> 6;
  if ((tid & 63) == 0) { ssum[wv] = sum; ssq[wv] = sq; }
  __syncthreads();
  sum = ssum[0] + ssum[1] + ssum[2] + ssum[3];
  sq = ssq[0] + ssq[1] + ssq[2] + ssq[3];
  float mean = sum * (1.f / DM);
  float var = sq * (1.f / DM) - mean * mean;
  float rstd = rsqrtf(var + 1e-5f);
  float* o = out + (long)row * DM;
  o[tid] = (x0 - mean) * rstd * g[tid] + bb[tid];
  o[tid + 256] = (x1 - mean) * rstd * g[tid + 256] + bb[tid + 256];
}

// ---------------------------------------------------------------------------
// Orchestration. fp32 everywhere. Workspace: 3 slots x 32 MB = 96 MB.
//  S0: xs1 -> dt1 -> xs2 -> dt2 -> newx(16MB) / xln(16MB @ +16MB)
//  S1: xc1 -> y1 (in place) -> y1*silu(z1) (in place) -> ffn chunk
//  S2: xc2 -> y2 -> y2*silu(z2) -> outacc (16MB)
//  xdbl1/xdbl2 (2MB each): head of d_out, fully overwritten by final LN2.
// ---------------------------------------------------------------------------
extern "C" void kernel_launch(void* const* d_in, const int* in_sizes, int n_in,
                              void* d_out, int out_size, void* d_ws, size_t ws_size,
                              hipStream_t stream) {
  const float* x = (const float*)d_in[0];
  const float* in1_w = (const float*)d_in[1];
  const float* conv1_w = (const float*)d_in[2];
  const float* conv1_b = (const float*)d_in[3];
  const float* xp1_w = (const float*)d_in[4];
  const float* dtp1_w = (const float*)d_in[5];
  const float* dtp1_b = (const float*)d_in[6];
  const float* Alog1 = (const float*)d_in[7];
  const float* D1 = (const float*)d_in[8];
  const float* outp1_w = (const float*)d_in[9];
  const float* in2_w = (const float*)d_in[10];
  const float* conv2_w = (const float*)d_in[11];
  const float* conv2_b = (const float*)d_in[12];
  const float* xp2_w = (const float*)d_in[13];
  const float* dtp2_w = (const float*)d_in[14];
  const float* dtp2_b = (const float*)d_in[15];
  const float* Alog2 = (const float*)d_in[16];
  const float* D2 = (const float*)d_in[17];
  const float* outp2_w = (const float*)d_in[18];
  const float* c1_w = (const float*)d_in[19];
  const float* c1_b = (const float*)d_in[20];
  const float* c2_w = (const float*)d_in[21];
  const float* c2_b = (const float*)d_in[22];
  const float* ln1_g = (const float*)d_in[23];
  const float* ln1_b = (const float*)d_in[24];
  const float* ln2_g = (const float*)d_in[25];
  const float* ln2_b = (const float*)d_in[26];

  const long SLOT = 8L * 1024 * 1024;   // 8M floats = 32 MB
  float* S0 = (float*)d_ws;
  float* S1 = S0 + SLOT;
  float* S2 = S1 + SLOT;
  float* newx = S0;                     // 4M floats
  float* xln = S0 + 4 * 1024 * 1024;    // 4M floats
  float* outacc = S2;                   // 4M floats
  float* xdbl = (float*)d_out;          // 512K floats scratch in d_out

  dim3 blk(256);
  auto grid = [](int N) { return dim3(N / BN, MROWS / BM); };

  // ---- direction 1 ----
  gemm_k<EPI_NONE, false, false><<<grid(DIN), blk, 0, stream>>>(
      x, DM, in1_w, DM, S0, DIN, nullptr, nullptr, DM);                   // xs1
  conv_silu_k<<<(MROWS * DIN) / 256, blk, 0, stream>>>(S0, conv1_w, conv1_b, S1);
  gemm_k<EPI_NONE, false, false><<<grid(64), blk, 0, stream>>>(
      S1, DIN, xp1_w, DIN, xdbl, 64, nullptr, nullptr, DIN);              // xdbl1
  gemm_k<EPI_BIAS_SOFTPLUS, false, false><<<grid(DIN), blk, 0, stream>>>(
      xdbl, 64, dtp1_w, DTRANK, S0, DIN, dtp1_b, nullptr, DTRANK);        // dt1
  scan_k<<<B_SZ * (DIN / 16), blk, 0, stream>>>(S0, S1, xdbl,
                                                Alog1, D1, S1);           // y1
  gemm_k<EPI_GATE, false, false><<<grid(DIN), blk, 0, stream>>>(
      x, DM, in1_w + (long)DIN * DM, DM, S1, DIN, nullptr, nullptr, DM);  // y1*=silu(z1)

  // ---- direction 2 (flipped sequence) ----
  gemm_k<EPI_NONE, true, false><<<grid(DIN), blk, 0, stream>>>(
      x, DM, in2_w, DM, S0, DIN, nullptr, nullptr, DM);                   // xs2
  conv_silu_k<<<(MROWS * DIN) / 256, blk, 0, stream>>>(S0, conv2_w, conv2_b, S2);
  gemm_k<EPI_NONE, false, false><<<grid(64), blk, 0, stream>>>(
      S2, DIN, xp2_w, DIN, xdbl, 64, nullptr, nullptr, DIN);              // xdbl2
  gemm_k<EPI_BIAS_SOFTPLUS, false, false><<<grid(DIN), blk, 0, stream>>>(
      xdbl, 64, dtp2_w, DTRANK, S0, DIN, dtp2_b, nullptr, DTRANK);        // dt2
  scan_k<<<B_SZ * (DIN / 16), blk, 0, stream>>>(S0, S2, xdbl,
                                                Alog2, D2, S2);           // y2
  gemm_k<EPI_GATE, true, false><<<grid(DIN), blk, 0, stream>>>(
      x, DM, in2_w + (long)DIN * DM, DM, S2, DIN, nullptr, nullptr, DM);  // y2*=silu(z2)

  // ---- merge: newx = y1@W1^T + flip(y2)@W2^T + x ----
  merge_k<<<grid(DM), blk, 0, stream>>>(S1, S2, outp1_w, outp2_w, x, newx);

  // ---- LN1 ----
  ln_k<<<MROWS, blk, 0, stream>>>(newx, ln1_g, ln1_b, xln);

  // ---- FFN, chunked over DFF (2 chunks of 1024) ----
  gemm_k<EPI_BIAS_GELU, false, false><<<grid(1024), blk, 0, stream>>>(
      xln, DM, c1_w, DM, S1, 1024, c1_b, nullptr, DM);
  gemm_k<EPI_BIAS_RES, false, false><<<grid(DM), blk, 0, stream>>>(
      S1, 1024, c2_w, DFF, outacc, DM, c2_b, xln, 1024);
  gemm_k<EPI_BIAS_GELU, false, false><<<grid(1024), blk, 0, stream>>>(
      xln, DM, c1_w + 1024L * DM, DM, S1, 1024, c1_b + 1024, nullptr, DM);
  gemm_k<EPI_NONE, false, true><<<grid(DM), blk, 0, stream>>>(
      S1, 1024, c2_w + 1024, DFF, outacc, DM, nullptr, nullptr, 1024);

  // ---- LN2 -> fp32 out (overwrites xdbl scratch) ----
  ln_k<<<MROWS, blk, 0, stream>>>(outacc, ln2_g, ln2_b, (float*)d_out);
}

// Round 6
// 2015.193 us; speedup vs baseline: 1.6187x; 1.2536x over previous
//
#include <hip/hip_runtime.h>
#include <math.h>

// ---------------------------------------------------------------------------
// Problem constants
// ---------------------------------------------------------------------------
#define B_SZ 8
#define L_SZ 1024
#define DM 512          // d_model
#define DFF 2048        // d_ff
#define DIN 1024        // expand * d_model
#define DSTATE 16
#define DTRANK 32
#define MROWS (B_SZ * L_SZ)   // 8192

// ---------------------------------------------------------------------------
// Tiled fp32 GEMM: C(M,N) = A(M,K) @ W(N,K)^T with epilogues.
// M = 8192; N % 64 == 0; K % 16 == 0 for all calls here.
// ---------------------------------------------------------------------------
constexpr int EPI_NONE = 0;
constexpr int EPI_BIAS_GELU = 1;      // + bias[col], exact gelu
constexpr int EPI_BIAS_RES = 2;       // + bias[col] + res[row, col]
constexpr int EPI_GATE = 3;           // C[r,c] = C[r,c] * silu(acc)
constexpr int EPI_BIAS_SOFTPLUS = 4;  // softplus(acc + bias[col])

#define BM 64
#define BN 64
#define BKK 16

template <int EPI, bool FLIPA, bool ACCUM>
__global__ __launch_bounds__(256) void gemm_k(
    const float* __restrict__ A, int lda,
    const float* __restrict__ W, int ldw,
    float* __restrict__ C, int ldc,
    const float* __restrict__ bias,
    const float* __restrict__ res,
    int K) {
  __shared__ float As[BKK][BM + 4];
  __shared__ float Ws[BKK][BN + 4];
  const int tid = threadIdx.x;
  const int m0 = blockIdx.y * BM;
  const int n0 = blockIdx.x * BN;
  const int tx = tid & 15;
  const int ty = tid >> 4;
  const int lrow = tid >> 2;        // 0..63
  const int lcol = (tid & 3) * 4;   // 0,4,8,12

  int arow = m0 + lrow;
  if (FLIPA) { int t = arow & (L_SZ - 1); arow = (arow - t) + (L_SZ - 1 - t); }
  const float* Arow = A + (long)arow * lda;
  const float* Wrow = W + (long)(n0 + lrow) * ldw;

  float acc[4][4] = {};
  for (int k0 = 0; k0 < K; k0 += BKK) {
    float4 av = *(const float4*)(Arow + k0 + lcol);
    float4 wv = *(const float4*)(Wrow + k0 + lcol);
    As[lcol + 0][lrow] = av.x; As[lcol + 1][lrow] = av.y;
    As[lcol + 2][lrow] = av.z; As[lcol + 3][lrow] = av.w;
    Ws[lcol + 0][lrow] = wv.x; Ws[lcol + 1][lrow] = wv.y;
    Ws[lcol + 2][lrow] = wv.z; Ws[lcol + 3][lrow] = wv.w;
    __syncthreads();
#pragma unroll
    for (int k = 0; k < BKK; ++k) {
      float a[4], b[4];
#pragma unroll
      for (int i = 0; i < 4; ++i) a[i] = As[k][ty * 4 + i];
#pragma unroll
      for (int j = 0; j < 4; ++j) b[j] = Ws[k][tx * 4 + j];
#pragma unroll
      for (int i = 0; i < 4; ++i)
#pragma unroll
        for (int j = 0; j < 4; ++j) acc[i][j] += a[i] * b[j];
    }
    __syncthreads();
  }

#pragma unroll
  for (int i = 0; i < 4; ++i) {
    int r = m0 + ty * 4 + i;
#pragma unroll
    for (int j = 0; j < 4; ++j) {
      int c = n0 + tx * 4 + j;
      long oi = (long)r * ldc + c;
      float v = acc[i][j];
      if (EPI == EPI_BIAS_GELU) {
        v += bias[c];
        v = 0.5f * v * (1.f + erff(v * 0.70710678118654752440f));
      } else if (EPI == EPI_BIAS_RES) {
        v += bias[c] + res[oi];
      } else if (EPI == EPI_GATE) {
        float sz = v / (1.f + __expf(-v));   // silu(z)
        v = C[oi] * sz;
      } else if (EPI == EPI_BIAS_SOFTPLUS) {
        v += bias[c];
        v = (v > 20.f) ? v : log1pf(__expf(v));
      }
      if constexpr (ACCUM) {
        C[oi] += v;
      } else {
        C[oi] = v;
      }
    }
  }
}

// ---------------------------------------------------------------------------
// Fused merge: newx(M,DM) = y1 @ W1^T + flip_L(y2) @ W2^T + xres.
// Composite K-loop of 2*DIN; second phase reads y2 rows L-flipped.
// ---------------------------------------------------------------------------
__global__ __launch_bounds__(256) void merge_k(
    const float* __restrict__ y1, const float* __restrict__ y2,
    const float* __restrict__ W1, const float* __restrict__ W2,
    const float* __restrict__ xres, float* __restrict__ newx) {
  __shared__ float As[BKK][BM + 4];
  __shared__ float Ws[BKK][BN + 4];
  const int tid = threadIdx.x;
  const int m0 = blockIdx.y * BM;
  const int n0 = blockIdx.x * BN;
  const int tx = tid & 15;
  const int ty = tid >> 4;
  const int lrow = tid >> 2;
  const int lcol = (tid & 3) * 4;

  int r1 = m0 + lrow;
  int t = r1 & (L_SZ - 1);
  int r2 = (r1 - t) + (L_SZ - 1 - t);
  const float* A1 = y1 + (long)r1 * DIN;
  const float* A2 = y2 + (long)r2 * DIN;
  const float* Wr1 = W1 + (long)(n0 + lrow) * DIN;
  const float* Wr2 = W2 + (long)(n0 + lrow) * DIN;

  float acc[4][4] = {};
  for (int k0 = 0; k0 < 2 * DIN; k0 += BKK) {
    const bool ph2 = (k0 >= DIN);
    const int kk = ph2 ? (k0 - DIN) : k0;
    float4 av = *(const float4*)((ph2 ? A2 : A1) + kk + lcol);
    float4 wv = *(const float4*)((ph2 ? Wr2 : Wr1) + kk + lcol);
    As[lcol + 0][lrow] = av.x; As[lcol + 1][lrow] = av.y;
    As[lcol + 2][lrow] = av.z; As[lcol + 3][lrow] = av.w;
    Ws[lcol + 0][lrow] = wv.x; Ws[lcol + 1][lrow] = wv.y;
    Ws[lcol + 2][lrow] = wv.z; Ws[lcol + 3][lrow] = wv.w;
    __syncthreads();
#pragma unroll
    for (int k = 0; k < BKK; ++k) {
      float a[4], b[4];
#pragma unroll
      for (int i = 0; i < 4; ++i) a[i] = As[k][ty * 4 + i];
#pragma unroll
      for (int j = 0; j < 4; ++j) b[j] = Ws[k][tx * 4 + j];
#pragma unroll
      for (int i = 0; i < 4; ++i)
#pragma unroll
        for (int j = 0; j < 4; ++j) acc[i][j] += a[i] * b[j];
    }
    __syncthreads();
  }

#pragma unroll
  for (int i = 0; i < 4; ++i) {
    int r = m0 + ty * 4 + i;
#pragma unroll
    for (int j = 0; j < 4; ++j) {
      int c = n0 + tx * 4 + j;
      newx[(long)r * DM + c] = acc[i][j] + xres[(long)r * DM + c];
    }
  }
}

// ---------------------------------------------------------------------------
// Depthwise causal conv (k=4) + bias + silu. xs(B,L,DIN) -> xc. fp32.
// ---------------------------------------------------------------------------
__global__ __launch_bounds__(256) void conv_silu_k(
    const float* __restrict__ xs, const float* __restrict__ w,
    const float* __restrict__ b, float* __restrict__ xc) {
  long idx = (long)blockIdx.x * 256 + threadIdx.x;
  int d = (int)(idx & (DIN - 1));
  long bt = idx >> 10;              // 0..8191
  int t = (int)(bt & (L_SZ - 1));
  long base = bt * DIN + d;
  float acc = b[d];
  if (t >= 3) acc += xs[base - 3L * DIN] * w[d * 4 + 0];
  if (t >= 2) acc += xs[base - 2L * DIN] * w[d * 4 + 1];
  if (t >= 1) acc += xs[base - 1L * DIN] * w[d * 4 + 2];
  acc += xs[base] * w[d * 4 + 3];
  xc[base] = acc / (1.f + __expf(-acc));
}

// ---------------------------------------------------------------------------
// Selective scan + skip (u*D), dt precomputed, ungated output.
// One 16-lane group per (b, d); lane = state index s.
// Software-pipelined: groups of GRP=8 timesteps; the next group's 4 streams
// (dt,u,B,C) are prefetched into registers before computing the current
// group, keeping ~8 loads/wave in flight to hide the ~900-cycle HBM latency
// (stride-4KB reads never hit cache).
// ---------------------------------------------------------------------------
#define GRP 8
__global__ __launch_bounds__(256) void scan_k(
    const float* __restrict__ dt, const float* __restrict__ u,
    const float* __restrict__ xdbl,
    const float* __restrict__ Alog, const float* __restrict__ Dp,
    float* __restrict__ out) {
  int tid = threadIdx.x;
  int s = tid & 15;
  int gi = tid >> 4;                  // 16 groups per block
  int blk = blockIdx.x;               // 0..511
  int b = blk >> 6;
  int d = ((blk & 63) << 4) + gi;
  float A = -__expf(Alog[d * DSTATE + s]);
  float Dd = Dp[d];
  float h = 0.f;
  long iu = (long)b * L_SZ * DIN + d;         // compute cursor
  long ix = (long)b * L_SZ * 64 + DTRANK + s;
  float pdt[GRP], pu[GRP], pB[GRP], pC[GRP];
#pragma unroll
  for (int j = 0; j < GRP; ++j) {
    pdt[j] = dt[iu + (long)j * DIN];
    pu[j] = u[iu + (long)j * DIN];
    pB[j] = xdbl[ix + j * 64];
    pC[j] = xdbl[ix + j * 64 + DSTATE];
  }
  long il = iu + (long)GRP * DIN;             // prefetch cursors
  long ixl = ix + GRP * 64;
  for (int t = 0; t < L_SZ; t += GRP) {
    float cdt[GRP], cu[GRP], cB[GRP], cC[GRP];
#pragma unroll
    for (int j = 0; j < GRP; ++j) {
      cdt[j] = pdt[j]; cu[j] = pu[j]; cB[j] = pB[j]; cC[j] = pC[j];
    }
    if (t + GRP < L_SZ) {
#pragma unroll
      for (int j = 0; j < GRP; ++j) {
        pdt[j] = dt[il + (long)j * DIN];
        pu[j] = u[il + (long)j * DIN];
        pB[j] = xdbl[ixl + j * 64];
        pC[j] = xdbl[ixl + j * 64 + DSTATE];
      }
    }
    il += (long)GRP * DIN;
    ixl += GRP * 64;
#pragma unroll
    for (int j = 0; j < GRP; ++j) {
      float da = __expf(cdt[j] * A);
      h = da * h + (cdt[j] * cu[j]) * cB[j];
      float p = h * cC[j];
      p += __shfl_xor(p, 1, 16);
      p += __shfl_xor(p, 2, 16);
      p += __shfl_xor(p, 4, 16);
      p += __shfl_xor(p, 8, 16);
      if (s == 0) out[iu + (long)j * DIN] = p + Dd * cu[j];
    }
    iu += (long)GRP * DIN;
  }
}

// ---------------------------------------------------------------------------
// LayerNorm over last dim (512). One block per row. fp32 -> fp32.
// ---------------------------------------------------------------------------
__global__ __launch_bounds__(256) void ln_k(
    const float* __restrict__ xin, const float* __restrict__ g,
    const float* __restrict__ bb, float* __restrict__ out) {
  int row = blockIdx.x;
  const float* p = xin + (long)row * DM;
  int tid = threadIdx.x;
  float x0 = p[tid], x1 = p[tid + 256];
  float sum = x0 + x1;
  float sq = x0 * x0 + x1 * x1;
#pragma unroll
  for (int o = 1; o < 64; o <<= 1) {
    sum += __shfl_xor(sum, o, 64);
    sq += __shfl_xor(sq, o, 64);
  }
  __shared__ float ssum[4], ssq[4];
  int wv = tid >> 6;
  if ((tid & 63) == 0) { ssum[wv] = sum; ssq[wv] = sq; }
  __syncthreads();
  sum = ssum[0] + ssum[1] + ssum[2] + ssum[3];
  sq = ssq[0] + ssq[1] + ssq[2] + ssq[3];
  float mean = sum * (1.f / DM);
  float var = sq * (1.f / DM) - mean * mean;
  float rstd = rsqrtf(var + 1e-5f);
  float* o = out + (long)row * DM;
  o[tid] = (x0 - mean) * rstd * g[tid] + bb[tid];
  o[tid + 256] = (x1 - mean) * rstd * g[tid + 256] + bb[tid + 256];
}

// ---------------------------------------------------------------------------
// Orchestration. fp32 everywhere. Workspace: 3 slots x 32 MB = 96 MB.
//  S0: xs1 -> dt1 -> xs2 -> dt2 -> newx(16MB) / xln(16MB @ +16MB)
//  S1: xc1 -> y1 (in place) -> y1*silu(z1) (in place) -> ffn chunk
//  S2: xc2 -> y2 -> y2*silu(z2) -> outacc (16MB)
//  xdbl (2MB): head of d_out, fully overwritten by final LN2.
// ---------------------------------------------------------------------------
extern "C" void kernel_launch(void* const* d_in, const int* in_sizes, int n_in,
                              void* d_out, int out_size, void* d_ws, size_t ws_size,
                              hipStream_t stream) {
  const float* x = (const float*)d_in[0];
  const float* in1_w = (const float*)d_in[1];
  const float* conv1_w = (const float*)d_in[2];
  const float* conv1_b = (const float*)d_in[3];
  const float* xp1_w = (const float*)d_in[4];
  const float* dtp1_w = (const float*)d_in[5];
  const float* dtp1_b = (const float*)d_in[6];
  const float* Alog1 = (const float*)d_in[7];
  const float* D1 = (const float*)d_in[8];
  const float* outp1_w = (const float*)d_in[9];
  const float* in2_w = (const float*)d_in[10];
  const float* conv2_w = (const float*)d_in[11];
  const float* conv2_b = (const float*)d_in[12];
  const float* xp2_w = (const float*)d_in[13];
  const float* dtp2_w = (const float*)d_in[14];
  const float* dtp2_b = (const float*)d_in[15];
  const float* Alog2 = (const float*)d_in[16];
  const float* D2 = (const float*)d_in[17];
  const float* outp2_w = (const float*)d_in[18];
  const float* c1_w = (const float*)d_in[19];
  const float* c1_b = (const float*)d_in[20];
  const float* c2_w = (const float*)d_in[21];
  const float* c2_b = (const float*)d_in[22];
  const float* ln1_g = (const float*)d_in[23];
  const float* ln1_b = (const float*)d_in[24];
  const float* ln2_g = (const float*)d_in[25];
  const float* ln2_b = (const float*)d_in[26];

  const long SLOT = 8L * 1024 * 1024;   // 8M floats = 32 MB
  float* S0 = (float*)d_ws;
  float* S1 = S0 + SLOT;
  float* S2 = S1 + SLOT;
  float* newx = S0;                     // 4M floats
  float* xln = S0 + 4 * 1024 * 1024;    // 4M floats
  float* outacc = S2;                   // 4M floats
  float* xdbl = (float*)d_out;          // 512K floats scratch in d_out

  dim3 blk(256);
  auto grid = [](int N) { return dim3(N / BN, MROWS / BM); };

  // ---- direction 1 ----
  gemm_k<EPI_NONE, false, false><<<grid(DIN), blk, 0, stream>>>(
      x, DM, in1_w, DM, S0, DIN, nullptr, nullptr, DM);                   // xs1
  conv_silu_k<<<(MROWS * DIN) / 256, blk, 0, stream>>>(S0, conv1_w, conv1_b, S1);
  gemm_k<EPI_NONE, false, false><<<grid(64), blk, 0, stream>>>(
      S1, DIN, xp1_w, DIN, xdbl, 64, nullptr, nullptr, DIN);              // xdbl1
  gemm_k<EPI_BIAS_SOFTPLUS, false, false><<<grid(DIN), blk, 0, stream>>>(
      xdbl, 64, dtp1_w, DTRANK, S0, DIN, dtp1_b, nullptr, DTRANK);        // dt1
  scan_k<<<B_SZ * (DIN / 16), blk, 0, stream>>>(S0, S1, xdbl,
                                                Alog1, D1, S1);           // y1
  gemm_k<EPI_GATE, false, false><<<grid(DIN), blk, 0, stream>>>(
      x, DM, in1_w + (long)DIN * DM, DM, S1, DIN, nullptr, nullptr, DM);  // y1*=silu(z1)

  // ---- direction 2 (flipped sequence) ----
  gemm_k<EPI_NONE, true, false><<<grid(DIN), blk, 0, stream>>>(
      x, DM, in2_w, DM, S0, DIN, nullptr, nullptr, DM);                   // xs2
  conv_silu_k<<<(MROWS * DIN) / 256, blk, 0, stream>>>(S0, conv2_w, conv2_b, S2);
  gemm_k<EPI_NONE, false, false><<<grid(64), blk, 0, stream>>>(
      S2, DIN, xp2_w, DIN, xdbl, 64, nullptr, nullptr, DIN);              // xdbl2
  gemm_k<EPI_BIAS_SOFTPLUS, false, false><<<grid(DIN), blk, 0, stream>>>(
      xdbl, 64, dtp2_w, DTRANK, S0, DIN, dtp2_b, nullptr, DTRANK);        // dt2
  scan_k<<<B_SZ * (DIN / 16), blk, 0, stream>>>(S0, S2, xdbl,
                                                Alog2, D2, S2);           // y2
  gemm_k<EPI_GATE, true, false><<<grid(DIN), blk, 0, stream>>>(
      x, DM, in2_w + (long)DIN * DM, DM, S2, DIN, nullptr, nullptr, DM);  // y2*=silu(z2)

  // ---- merge: newx = y1@W1^T + flip(y2)@W2^T + x ----
  merge_k<<<grid(DM), blk, 0, stream>>>(S1, S2, outp1_w, outp2_w, x, newx);

  // ---- LN1 ----
  ln_k<<<MROWS, blk, 0, stream>>>(newx, ln1_g, ln1_b, xln);

  // ---- FFN, chunked over DFF (2 chunks of 1024) ----
  gemm_k<EPI_BIAS_GELU, false, false><<<grid(1024), blk, 0, stream>>>(
      xln, DM, c1_w, DM, S1, 1024, c1_b, nullptr, DM);
  gemm_k<EPI_BIAS_RES, false, false><<<grid(DM), blk, 0, stream>>>(
      S1, 1024, c2_w, DFF, outacc, DM, c2_b, xln, 1024);
  gemm_k<EPI_BIAS_GELU, false, false><<<grid(1024), blk, 0, stream>>>(
      xln, DM, c1_w + 1024L * DM, DM, S1, 1024, c1_b + 1024, nullptr, DM);
  gemm_k<EPI_NONE, false, true><<<grid(DM), blk, 0, stream>>>(
      S1, 1024, c2_w + 1024, DFF, outacc, DM, nullptr, nullptr, 1024);

  // ---- LN2 -> fp32 out (overwrites xdbl scratch) ----
  ln_k<<<MROWS, blk, 0, stream>>>(outacc, ln2_g, ln2_b, (float*)d_out);
}

// Round 7
// 1288.803 us; speedup vs baseline: 2.5310x; 1.5636x over previous
//
#include <hip/hip_runtime.h>
#include <hip/hip_bf16.h>
#include <math.h>

// ---------------------------------------------------------------------------
// Problem constants
// ---------------------------------------------------------------------------
#define B_SZ 8
#define L_SZ 1024
#define DM 512          // d_model
#define DFF 2048        // d_ff
#define DIN 1024        // expand * d_model
#define DSTATE 16
#define DTRANK 32
#define MROWS (B_SZ * L_SZ)   // 8192

typedef __hip_bfloat16 bf16;
typedef unsigned short u16;
using f32x4 = __attribute__((ext_vector_type(4))) float;
using bfrag = __attribute__((ext_vector_type(8))) short;   // 8 bf16 = 4 VGPR

__device__ inline float ldf(const float* p, long i) { return p[i]; }
__device__ inline float ldf(const bf16* p, long i) {
  return __uint_as_float((unsigned)((const u16*)p)[i] << 16);
}
__device__ inline void stf(float* p, long i, float v) { p[i] = v; }
__device__ inline void stf(bf16* p, long i, float v) { p[i] = __float2bfloat16(v); }
__device__ inline float4 ld4f(const float* p) { return *(const float4*)p; }
__device__ inline float4 ld4f(const bf16* p) {
  ushort4 u = *(const ushort4*)p;
  float4 v;
  v.x = __uint_as_float((unsigned)u.x << 16);
  v.y = __uint_as_float((unsigned)u.y << 16);
  v.z = __uint_as_float((unsigned)u.z << 16);
  v.w = __uint_as_float((unsigned)u.w << 16);
  return v;
}

// ---------------------------------------------------------------------------
// fp32 -> bf16 convert
// ---------------------------------------------------------------------------
__global__ __launch_bounds__(256) void cvt_k(const float* __restrict__ s,
                                             bf16* __restrict__ d, int n) {
  int i = blockIdx.x * 256 + threadIdx.x;
  if (i < n) d[i] = __float2bfloat16(s[i]);
}

// ---------------------------------------------------------------------------
// bf16 MFMA GEMM: C(M,N) = A(M,K) @ W(N,K)^T, fp32 accumulate.
// 128x128 tile, BK=32, 256 threads = 4 waves in 2x2, each wave 64x64 via
// 4x4 grid of v_mfma_f32_16x16x32_bf16.
// A,W bf16 row-major (K contiguous). M%128==0, N%128==0, K%32==0.
// ---------------------------------------------------------------------------
constexpr int MEPI_STORE_BF16 = 0;  // store bf16
constexpr int MEPI_GATE = 1;        // C[oi] = C[oi] * silu(acc), bf16 in-place
constexpr int MEPI_BIAS_GELU = 2;   // bf16 out
constexpr int MEPI_BIAS_RES = 3;    // fp32 out = acc + bias + res
constexpr int MEPI_ACCUM_F32 = 4;   // fp32 C += acc

template <int EPI, bool FLIPA, typename TO>
__global__ __launch_bounds__(256) void mgemm_k(
    const bf16* __restrict__ Ab, int lda,
    const bf16* __restrict__ Wb, int ldw,
    TO* __restrict__ C, int ldc,
    const float* __restrict__ bias,
    const float* __restrict__ res,
    int K) {
  __shared__ u16 Asm[128][40];
  __shared__ u16 Wsm[128][40];
  const int tid = threadIdx.x;
  const int m0 = blockIdx.y * 128;
  const int n0 = blockIdx.x * 128;

  // staging: thread t loads 16 elems of row t>>1, half (t&1)
  const int srow = tid >> 1;
  const int scol = (tid & 1) * 16;
  int ar = m0 + srow;
  if (FLIPA) { int t = ar & (L_SZ - 1); ar = (ar - t) + (L_SZ - 1 - t); }
  const u16* Ag = (const u16*)Ab + (long)ar * lda + scol;
  const u16* Wg = (const u16*)Wb + (long)(n0 + srow) * ldw + scol;

  const int lane = tid & 63, quad = lane >> 4, l16 = lane & 15;
  const int wid = tid >> 6;
  const int wm = (wid & 1) * 64, wn = (wid >> 1) * 64;

  f32x4 acc[4][4];
#pragma unroll
  for (int i = 0; i < 4; ++i)
#pragma unroll
    for (int j = 0; j < 4; ++j) acc[i][j] = {0.f, 0.f, 0.f, 0.f};

  for (int k0 = 0; k0 < K; k0 += 32) {
    uint4 av0 = *(const uint4*)(Ag + k0);
    uint4 av1 = *(const uint4*)(Ag + k0 + 8);
    uint4 wv0 = *(const uint4*)(Wg + k0);
    uint4 wv1 = *(const uint4*)(Wg + k0 + 8);
    __syncthreads();
    *(uint4*)&Asm[srow][scol] = av0;
    *(uint4*)&Asm[srow][scol + 8] = av1;
    *(uint4*)&Wsm[srow][scol] = wv0;
    *(uint4*)&Wsm[srow][scol + 8] = wv1;
    __syncthreads();
    bfrag a[4], b[4];
#pragma unroll
    for (int mi = 0; mi < 4; ++mi)
      a[mi] = *(const bfrag*)&Asm[wm + mi * 16 + l16][quad * 8];
#pragma unroll
    for (int ni = 0; ni < 4; ++ni)
      b[ni] = *(const bfrag*)&Wsm[wn + ni * 16 + l16][quad * 8];
#pragma unroll
    for (int mi = 0; mi < 4; ++mi)
#pragma unroll
      for (int ni = 0; ni < 4; ++ni)
        acc[mi][ni] = __builtin_amdgcn_mfma_f32_16x16x32_bf16(
            a[mi], b[ni], acc[mi][ni], 0, 0, 0);
  }

#pragma unroll
  for (int mi = 0; mi < 4; ++mi)
#pragma unroll
    for (int ni = 0; ni < 4; ++ni)
#pragma unroll
      for (int r = 0; r < 4; ++r) {
        int row = m0 + wm + mi * 16 + quad * 4 + r;
        int col = n0 + wn + ni * 16 + l16;
        long oi = (long)row * ldc + col;
        float v = acc[mi][ni][r];
        if (EPI == MEPI_STORE_BF16) {
          stf(C, oi, v);
        } else if (EPI == MEPI_GATE) {
          float y = ldf((const bf16*)C, oi);
          float sz = v / (1.f + __expf(-v));
          stf(C, oi, y * sz);
        } else if (EPI == MEPI_BIAS_GELU) {
          v += bias[col];
          v = 0.5f * v * (1.f + erff(v * 0.70710678118654752440f));
          stf(C, oi, v);
        } else if (EPI == MEPI_BIAS_RES) {
          ((float*)C)[oi] = v + bias[col] + res[oi];
        } else if (EPI == MEPI_ACCUM_F32) {
          ((float*)C)[oi] += v;
        }
      }
}

// ---------------------------------------------------------------------------
// MFMA merge: newx(M,DM) = y1 @ W1^T + flip_L(y2) @ W2^T + xres (fp32 out).
// Composite K of 2*DIN; phase 2 reads y2 rows L-flipped. All operands bf16.
// ---------------------------------------------------------------------------
__global__ __launch_bounds__(256) void mmerge_k(
    const bf16* __restrict__ y1, const bf16* __restrict__ y2,
    const bf16* __restrict__ W1, const bf16* __restrict__ W2,
    const float* __restrict__ xres, float* __restrict__ newx) {
  __shared__ u16 Asm[128][40];
  __shared__ u16 Wsm[128][40];
  const int tid = threadIdx.x;
  const int m0 = blockIdx.y * 128;
  const int n0 = blockIdx.x * 128;

  const int srow = tid >> 1;
  const int scol = (tid & 1) * 16;
  int r1 = m0 + srow;
  int tt = r1 & (L_SZ - 1);
  int r2 = (r1 - tt) + (L_SZ - 1 - tt);
  const u16* A1g = (const u16*)y1 + (long)r1 * DIN + scol;
  const u16* A2g = (const u16*)y2 + (long)r2 * DIN + scol;
  const u16* W1g = (const u16*)W1 + (long)(n0 + srow) * DIN + scol;
  const u16* W2g = (const u16*)W2 + (long)(n0 + srow) * DIN + scol;

  const int lane = tid & 63, quad = lane >> 4, l16 = lane & 15;
  const int wid = tid >> 6;
  const int wm = (wid & 1) * 64, wn = (wid >> 1) * 64;

  f32x4 acc[4][4];
#pragma unroll
  for (int i = 0; i < 4; ++i)
#pragma unroll
    for (int j = 0; j < 4; ++j) acc[i][j] = {0.f, 0.f, 0.f, 0.f};

  for (int k0 = 0; k0 < 2 * DIN; k0 += 32) {
    const bool ph2 = (k0 >= DIN);
    const int kk = k0 & (DIN - 1);
    const u16* Ag = ph2 ? A2g : A1g;
    const u16* Wg = ph2 ? W2g : W1g;
    uint4 av0 = *(const uint4*)(Ag + kk);
    uint4 av1 = *(const uint4*)(Ag + kk + 8);
    uint4 wv0 = *(const uint4*)(Wg + kk);
    uint4 wv1 = *(const uint4*)(Wg + kk + 8);
    __syncthreads();
    *(uint4*)&Asm[srow][scol] = av0;
    *(uint4*)&Asm[srow][scol + 8] = av1;
    *(uint4*)&Wsm[srow][scol] = wv0;
    *(uint4*)&Wsm[srow][scol + 8] = wv1;
    __syncthreads();
    bfrag a[4], b[4];
#pragma unroll
    for (int mi = 0; mi < 4; ++mi)
      a[mi] = *(const bfrag*)&Asm[wm + mi * 16 + l16][quad * 8];
#pragma unroll
    for (int ni = 0; ni < 4; ++ni)
      b[ni] = *(const bfrag*)&Wsm[wn + ni * 16 + l16][quad * 8];
#pragma unroll
    for (int mi = 0; mi < 4; ++mi)
#pragma unroll
      for (int ni = 0; ni < 4; ++ni)
        acc[mi][ni] = __builtin_amdgcn_mfma_f32_16x16x32_bf16(
            a[mi], b[ni], acc[mi][ni], 0, 0, 0);
  }

#pragma unroll
  for (int mi = 0; mi < 4; ++mi)
#pragma unroll
    for (int ni = 0; ni < 4; ++ni)
#pragma unroll
      for (int r = 0; r < 4; ++r) {
        int row = m0 + wm + mi * 16 + quad * 4 + r;
        int col = n0 + wn + ni * 16 + l16;
        long oi = (long)row * DM + col;
        newx[oi] = acc[mi][ni][r] + xres[oi];
      }
}

// ---------------------------------------------------------------------------
// Small fp32-compute GEMM (vector ALU): C = A @ W^T. For xdbl (N=64) and
// dt (K=32) where MFMA overhead isn't worth it. TA: float or bf16 A.
// ---------------------------------------------------------------------------
constexpr int EPI_NONE = 0;
constexpr int EPI_BIAS_SOFTPLUS = 1;

#define BM 64
#define BN 64
#define BKK 16

template <int EPI, typename TA, typename TO>
__global__ __launch_bounds__(256) void gemm_k(
    const TA* __restrict__ A, int lda,
    const float* __restrict__ W, int ldw,
    TO* __restrict__ C, int ldc,
    const float* __restrict__ bias, int K) {
  __shared__ float As[BKK][BM + 4];
  __shared__ float Ws[BKK][BN + 4];
  const int tid = threadIdx.x;
  const int m0 = blockIdx.y * BM;
  const int n0 = blockIdx.x * BN;
  const int tx = tid & 15;
  const int ty = tid >> 4;
  const int lrow = tid >> 2;
  const int lcol = (tid & 3) * 4;

  const TA* Arow = A + (long)(m0 + lrow) * lda;
  const float* Wrow = W + (long)(n0 + lrow) * ldw;

  float acc[4][4] = {};
  for (int k0 = 0; k0 < K; k0 += BKK) {
    float4 av = ld4f(Arow + k0 + lcol);
    float4 wv = ld4f(Wrow + k0 + lcol);
    As[lcol + 0][lrow] = av.x; As[lcol + 1][lrow] = av.y;
    As[lcol + 2][lrow] = av.z; As[lcol + 3][lrow] = av.w;
    Ws[lcol + 0][lrow] = wv.x; Ws[lcol + 1][lrow] = wv.y;
    Ws[lcol + 2][lrow] = wv.z; Ws[lcol + 3][lrow] = wv.w;
    __syncthreads();
#pragma unroll
    for (int k = 0; k < BKK; ++k) {
      float a[4], b[4];
#pragma unroll
      for (int i = 0; i < 4; ++i) a[i] = As[k][ty * 4 + i];
#pragma unroll
      for (int j = 0; j < 4; ++j) b[j] = Ws[k][tx * 4 + j];
#pragma unroll
      for (int i = 0; i < 4; ++i)
#pragma unroll
        for (int j = 0; j < 4; ++j) acc[i][j] += a[i] * b[j];
    }
    __syncthreads();
  }

#pragma unroll
  for (int i = 0; i < 4; ++i) {
    int r = m0 + ty * 4 + i;
#pragma unroll
    for (int j = 0; j < 4; ++j) {
      int c = n0 + tx * 4 + j;
      float v = acc[i][j];
      if (EPI == EPI_BIAS_SOFTPLUS) {
        v += bias[c];
        v = (v > 20.f) ? v : log1pf(__expf(v));
      }
      stf(C, (long)r * ldc + c, v);
    }
  }
}

// ---------------------------------------------------------------------------
// Depthwise causal conv (k=4) + bias + silu. bf16 in/out, fp32 weights.
// ---------------------------------------------------------------------------
__global__ __launch_bounds__(256) void conv_silu_k(
    const bf16* __restrict__ xs, const float* __restrict__ w,
    const float* __restrict__ b, bf16* __restrict__ xc) {
  long idx = (long)blockIdx.x * 256 + threadIdx.x;
  int d = (int)(idx & (DIN - 1));
  long bt = idx >> 10;
  int t = (int)(bt & (L_SZ - 1));
  long base = bt * DIN + d;
  float acc = b[d];
  if (t >= 3) acc += ldf(xs, base - 3L * DIN) * w[d * 4 + 0];
  if (t >= 2) acc += ldf(xs, base - 2L * DIN) * w[d * 4 + 1];
  if (t >= 1) acc += ldf(xs, base - 1L * DIN) * w[d * 4 + 2];
  acc += ldf(xs, base) * w[d * 4 + 3];
  stf(xc, base, acc / (1.f + __expf(-acc)));
}

// ---------------------------------------------------------------------------
// Selective scan + skip (u*D). dt,u bf16; B,C fp32; out bf16 IN-PLACE over
// dt (write index always trails all reads). GRP-step register prefetch hides
// HBM latency. One 16-lane group per (b,d); lane = state index s.
// ---------------------------------------------------------------------------
#define GRP 8
__global__ __launch_bounds__(256) void scan_k(
    const bf16* __restrict__ dt, const bf16* __restrict__ u,
    const float* __restrict__ xdbl,
    const float* __restrict__ Alog, const float* __restrict__ Dp,
    bf16* __restrict__ out) {
  int tid = threadIdx.x;
  int s = tid & 15;
  int gi = tid >> 4;
  int blk = blockIdx.x;
  int b = blk >> 6;
  int d = ((blk & 63) << 4) + gi;
  float A = -__expf(Alog[d * DSTATE + s]);
  float Dd = Dp[d];
  float h = 0.f;
  long iu = (long)b * L_SZ * DIN + d;
  long ix = (long)b * L_SZ * 64 + DTRANK + s;
  float pdt[GRP], pu[GRP], pB[GRP], pC[GRP];
#pragma unroll
  for (int j = 0; j < GRP; ++j) {
    pdt[j] = ldf(dt, iu + (long)j * DIN);
    pu[j] = ldf(u, iu + (long)j * DIN);
    pB[j] = xdbl[ix + j * 64];
    pC[j] = xdbl[ix + j * 64 + DSTATE];
  }
  long il = iu + (long)GRP * DIN;
  long ixl = ix + GRP * 64;
  for (int t = 0; t < L_SZ; t += GRP) {
    float cdt[GRP], cu[GRP], cB[GRP], cC[GRP];
#pragma unroll
    for (int j = 0; j < GRP; ++j) {
      cdt[j] = pdt[j]; cu[j] = pu[j]; cB[j] = pB[j]; cC[j] = pC[j];
    }
    if (t + GRP < L_SZ) {
#pragma unroll
      for (int j = 0; j < GRP; ++j) {
        pdt[j] = ldf(dt, il + (long)j * DIN);
        pu[j] = ldf(u, il + (long)j * DIN);
        pB[j] = xdbl[ixl + j * 64];
        pC[j] = xdbl[ixl + j * 64 + DSTATE];
      }
    }
    il += (long)GRP * DIN;
    ixl += GRP * 64;
#pragma unroll
    for (int j = 0; j < GRP; ++j) {
      float da = __expf(cdt[j] * A);
      h = da * h + (cdt[j] * cu[j]) * cB[j];
      float p = h * cC[j];
      p += __shfl_xor(p, 1, 16);
      p += __shfl_xor(p, 2, 16);
      p += __shfl_xor(p, 4, 16);
      p += __shfl_xor(p, 8, 16);
      if (s == 0) stf(out, iu + (long)j * DIN, p + Dd * cu[j]);
    }
    iu += (long)GRP * DIN;
  }
}

// ---------------------------------------------------------------------------
// LayerNorm over last dim (512). fp32 in; fp32 out + optional bf16 copy.
// ---------------------------------------------------------------------------
__global__ __launch_bounds__(256) void ln_k(
    const float* __restrict__ xin, const float* __restrict__ g,
    const float* __restrict__ bb, float* __restrict__ out,
    bf16* __restrict__ outb) {
  int row = blockIdx.x;
  const float* p = xin + (long)row * DM;
  int tid = threadIdx.x;
  float x0 = p[tid], x1 = p[tid + 256];
  float sum = x0 + x1;
  float sq = x0 * x0 + x1 * x1;
#pragma unroll
  for (int o = 1; o < 64; o <<= 1) {
    sum += __shfl_xor(sum, o, 64);
    sq += __shfl_xor(sq, o, 64);
  }
  __shared__ float ssum[4], ssq[4];
  int wv = tid >> 6;
  if ((tid & 63) == 0) { ssum[wv] = sum; ssq[wv] = sq; }
  __syncthreads();
  sum = ssum[0] + ssum[1] + ssum[2] + ssum[3];
  sq = ssq[0] + ssq[1] + ssq[2] + ssq[3];
  float mean = sum * (1.f / DM);
  float var = sq * (1.f / DM) - mean * mean;
  float rstd = rsqrtf(var + 1e-5f);
  float v0 = (x0 - mean) * rstd * g[tid] + bb[tid];
  float v1 = (x1 - mean) * rstd * g[tid + 256] + bb[tid + 256];
  out[(long)row * DM + tid] = v0;
  out[(long)row * DM + tid + 256] = v1;
  if (outb) {
    stf(outb, (long)row * DM + tid, v0);
    stf(outb, (long)row * DM + tid + 256, v1);
  }
}

// ---------------------------------------------------------------------------
// Orchestration. Workspace (90 MB total, slots in MB offsets):
//  xb [0,8): x as bf16
//  wb [8,18): bf16 weights: in1(1M) in2(1M) o1(.5M) o2(.5M) c1(1M) c2(1M)
//  sA [18,34): xs1 -> dt1 -> y1(in place) -> y1b(gated) -> outacc(fp32)
//  sB [34,50): xc1 -> xs2 -> dt2 -> y2b(gated)
//  sC [50,66): xc2 -> newx(fp32) -> ffn chunk(bf16)
//  sD [66,82): xln fp32
//  sE [82,90): xln bf16
//  xdbl (2 MB fp32): head of d_out, overwritten by final LN2.
// ---------------------------------------------------------------------------
extern "C" void kernel_launch(void* const* d_in, const int* in_sizes, int n_in,
                              void* d_out, int out_size, void* d_ws, size_t ws_size,
                              hipStream_t stream) {
  const float* x = (const float*)d_in[0];
  const float* in1_w = (const float*)d_in[1];
  const float* conv1_w = (const float*)d_in[2];
  const float* conv1_b = (const float*)d_in[3];
  const float* xp1_w = (const float*)d_in[4];
  const float* dtp1_w = (const float*)d_in[5];
  const float* dtp1_b = (const float*)d_in[6];
  const float* Alog1 = (const float*)d_in[7];
  const float* D1 = (const float*)d_in[8];
  const float* outp1_w = (const float*)d_in[9];
  const float* in2_w = (const float*)d_in[10];
  const float* conv2_w = (const float*)d_in[11];
  const float* conv2_b = (const float*)d_in[12];
  const float* xp2_w = (const float*)d_in[13];
  const float* dtp2_w = (const float*)d_in[14];
  const float* dtp2_b = (const float*)d_in[15];
  const float* Alog2 = (const float*)d_in[16];
  const float* D2 = (const float*)d_in[17];
  const float* outp2_w = (const float*)d_in[18];
  const float* c1_w = (const float*)d_in[19];
  const float* c1_b = (const float*)d_in[20];
  const float* c2_w = (const float*)d_in[21];
  const float* c2_b = (const float*)d_in[22];
  const float* ln1_g = (const float*)d_in[23];
  const float* ln1_b = (const float*)d_in[24];
  const float* ln2_g = (const float*)d_in[25];
  const float* ln2_b = (const float*)d_in[26];

  char* wsb = (char*)d_ws;
  const long MB = 1024L * 1024;
  bf16* xb = (bf16*)(wsb);
  bf16* wbb = (bf16*)(wsb + 8 * MB);
  bf16* in1b = wbb;
  bf16* in2b = wbb + 1048576L;
  bf16* o1b = wbb + 2097152L;
  bf16* o2b = wbb + 2621440L;
  bf16* c1b = wbb + 3145728L;
  bf16* c2b = wbb + 4194304L;
  bf16* sA = (bf16*)(wsb + 18 * MB);
  bf16* sB = (bf16*)(wsb + 34 * MB);
  bf16* sC = (bf16*)(wsb + 50 * MB);
  float* sCf = (float*)sC;          // newx
  float* sDf = (float*)(wsb + 66 * MB);  // xln fp32
  bf16* sE = (bf16*)(wsb + 82 * MB);     // xln bf16
  float* outacc = (float*)sA;
  float* xdbl = (float*)d_out;      // 512K floats scratch

  dim3 blk(256);
  dim3 gP(DIN / 128, MROWS / 128);      // N=1024 MFMA grids
  dim3 gM(DM / 128, MROWS / 128);       // N=512 MFMA grids

  // ---- weight + input conversion (bf16) ----
  cvt_k<<<(MROWS * DM) / 256, blk, 0, stream>>>(x, xb, MROWS * DM);
  cvt_k<<<(2 * DIN * DM) / 256, blk, 0, stream>>>(in1_w, in1b, 2 * DIN * DM);
  cvt_k<<<(2 * DIN * DM) / 256, blk, 0, stream>>>(in2_w, in2b, 2 * DIN * DM);
  cvt_k<<<(DM * DIN) / 256, blk, 0, stream>>>(outp1_w, o1b, DM * DIN);
  cvt_k<<<(DM * DIN) / 256, blk, 0, stream>>>(outp2_w, o2b, DM * DIN);
  cvt_k<<<(DFF * DM) / 256, blk, 0, stream>>>(c1_w, c1b, DFF * DM);
  cvt_k<<<(DM * DFF) / 256, blk, 0, stream>>>(c2_w, c2b, DM * DFF);

  // ---- direction 1 ----
  mgemm_k<MEPI_STORE_BF16, false, bf16><<<gP, blk, 0, stream>>>(
      xb, DM, in1b, DM, sA, DIN, nullptr, nullptr, DM);                  // xs1
  conv_silu_k<<<(MROWS * DIN) / 256, blk, 0, stream>>>(sA, conv1_w, conv1_b, sB);
  gemm_k<EPI_NONE, bf16, float><<<dim3(1, MROWS / BM), blk, 0, stream>>>(
      sB, DIN, xp1_w, DIN, xdbl, 64, nullptr, DIN);                      // xdbl1
  gemm_k<EPI_BIAS_SOFTPLUS, float, bf16><<<dim3(DIN / BN, MROWS / BM), blk, 0, stream>>>(
      xdbl, 64, dtp1_w, DTRANK, sA, DIN, dtp1_b, DTRANK);                // dt1
  scan_k<<<B_SZ * (DIN / 16), blk, 0, stream>>>(sA, sB, xdbl, Alog1, D1, sA);
  mgemm_k<MEPI_GATE, false, bf16><<<gP, blk, 0, stream>>>(
      xb, DM, in1b + (long)DIN * DM, DM, sA, DIN, nullptr, nullptr, DM); // y1b

  // ---- direction 2 (flipped sequence) ----
  mgemm_k<MEPI_STORE_BF16, true, bf16><<<gP, blk, 0, stream>>>(
      xb, DM, in2b, DM, sB, DIN, nullptr, nullptr, DM);                  // xs2
  conv_silu_k<<<(MROWS * DIN) / 256, blk, 0, stream>>>(sB, conv2_w, conv2_b, sC);
  gemm_k<EPI_NONE, bf16, float><<<dim3(1, MROWS / BM), blk, 0, stream>>>(
      sC, DIN, xp2_w, DIN, xdbl, 64, nullptr, DIN);                      // xdbl2
  gemm_k<EPI_BIAS_SOFTPLUS, float, bf16><<<dim3(DIN / BN, MROWS / BM), blk, 0, stream>>>(
      xdbl, 64, dtp2_w, DTRANK, sB, DIN, dtp2_b, DTRANK);                // dt2
  scan_k<<<B_SZ * (DIN / 16), blk, 0, stream>>>(sB, sC, xdbl, Alog2, D2, sB);
  mgemm_k<MEPI_GATE, true, bf16><<<gP, blk, 0, stream>>>(
      xb, DM, in2b + (long)DIN * DM, DM, sB, DIN, nullptr, nullptr, DM); // y2b

  // ---- merge: newx = y1@W1^T + flip(y2)@W2^T + x ----
  mmerge_k<<<gM, blk, 0, stream>>>(sA, sB, o1b, o2b, x, sCf);

  // ---- LN1 (fp32 + bf16 outputs) ----
  ln_k<<<MROWS, blk, 0, stream>>>(sCf, ln1_g, ln1_b, sDf, sE);

  // ---- FFN, 2 chunks of 1024 over DFF ----
  mgemm_k<MEPI_BIAS_GELU, false, bf16><<<gP, blk, 0, stream>>>(
      sE, DM, c1b, DM, sC, 1024, c1_b, nullptr, DM);
  mgemm_k<MEPI_BIAS_RES, false, float><<<gM, blk, 0, stream>>>(
      sC, 1024, c2b, DFF, outacc, DM, c2_b, sDf, 1024);
  mgemm_k<MEPI_BIAS_GELU, false, bf16><<<gP, blk, 0, stream>>>(
      sE, DM, c1b + 1024L * DM, DM, sC, 1024, c1_b + 1024, nullptr, DM);
  mgemm_k<MEPI_ACCUM_F32, false, float><<<gM, blk, 0, stream>>>(
      sC, 1024, c2b + 1024, DFF, outacc, DM, nullptr, nullptr, 1024);

  // ---- LN2 -> fp32 out (overwrites xdbl scratch) ----
  ln_k<<<MROWS, blk, 0, stream>>>(outacc, ln2_g, ln2_b, (float*)d_out, nullptr);
}

// Round 8
// 1105.861 us; speedup vs baseline: 2.9497x; 1.1654x over previous
//
#include <hip/hip_runtime.h>
#include <hip/hip_bf16.h>
#include <math.h>

// ---------------------------------------------------------------------------
// Problem constants
// ---------------------------------------------------------------------------
#define B_SZ 8
#define L_SZ 1024
#define DM 512          // d_model
#define DFF 2048        // d_ff
#define DIN 1024        // expand * d_model
#define DSTATE 16
#define DTRANK 32
#define MROWS (B_SZ * L_SZ)   // 8192

typedef __hip_bfloat16 bf16;
typedef unsigned short u16;
using f32x4 = __attribute__((ext_vector_type(4))) float;
using bfrag = __attribute__((ext_vector_type(8))) short;   // 8 bf16 = 4 VGPR

__device__ inline float ldf(const float* p, long i) { return p[i]; }
__device__ inline float ldf(const bf16* p, long i) {
  return __uint_as_float((unsigned)((const u16*)p)[i] << 16);
}
__device__ inline void stf(float* p, long i, float v) { p[i] = v; }
__device__ inline void stf(bf16* p, long i, float v) { p[i] = __float2bfloat16(v); }
__device__ inline float b2f(u16 x) {
  return __uint_as_float((unsigned)x << 16);
}
__device__ inline float4 ld4f(const float* p) { return *(const float4*)p; }
__device__ inline float4 ld4f(const bf16* p) {
  ushort4 u = *(const ushort4*)p;
  float4 v;
  v.x = b2f(u.x); v.y = b2f(u.y); v.z = b2f(u.z); v.w = b2f(u.w);
  return v;
}

// ---------------------------------------------------------------------------
// fp32 -> bf16 convert
// ---------------------------------------------------------------------------
__global__ __launch_bounds__(256) void cvt_k(const float* __restrict__ s,
                                             bf16* __restrict__ d, int n) {
  int i = blockIdx.x * 256 + threadIdx.x;
  if (i < n) d[i] = __float2bfloat16(s[i]);
}

// ---------------------------------------------------------------------------
// bf16 MFMA GEMM: C(M,N) = A(M,K) @ W(N,K)^T, fp32 accumulate.
// 128x128 tile, BK=32, 4 waves, each 64x64 via 4x4 v_mfma_f32_16x16x32_bf16.
// ---------------------------------------------------------------------------
constexpr int MEPI_STORE_BF16 = 0;
constexpr int MEPI_GATE = 1;        // C[oi] = C[oi] * silu(acc), bf16 in-place
constexpr int MEPI_BIAS_GELU = 2;   // bf16 out
constexpr int MEPI_BIAS_RES = 3;    // fp32 out = acc + bias + res
constexpr int MEPI_ACCUM_F32 = 4;   // fp32 C += acc

template <int EPI, bool FLIPA, typename TO>
__global__ __launch_bounds__(256) void mgemm_k(
    const bf16* __restrict__ Ab, int lda,
    const bf16* __restrict__ Wb, int ldw,
    TO* __restrict__ C, int ldc,
    const float* __restrict__ bias,
    const float* __restrict__ res,
    int K) {
  __shared__ u16 Asm[128][40];
  __shared__ u16 Wsm[128][40];
  const int tid = threadIdx.x;
  const int m0 = blockIdx.y * 128;
  const int n0 = blockIdx.x * 128;

  const int srow = tid >> 1;
  const int scol = (tid & 1) * 16;
  int ar = m0 + srow;
  if (FLIPA) { int t = ar & (L_SZ - 1); ar = (ar - t) + (L_SZ - 1 - t); }
  const u16* Ag = (const u16*)Ab + (long)ar * lda + scol;
  const u16* Wg = (const u16*)Wb + (long)(n0 + srow) * ldw + scol;

  const int lane = tid & 63, quad = lane >> 4, l16 = lane & 15;
  const int wid = tid >> 6;
  const int wm = (wid & 1) * 64, wn = (wid >> 1) * 64;

  f32x4 acc[4][4];
#pragma unroll
  for (int i = 0; i < 4; ++i)
#pragma unroll
    for (int j = 0; j < 4; ++j) acc[i][j] = {0.f, 0.f, 0.f, 0.f};

  for (int k0 = 0; k0 < K; k0 += 32) {
    uint4 av0 = *(const uint4*)(Ag + k0);
    uint4 av1 = *(const uint4*)(Ag + k0 + 8);
    uint4 wv0 = *(const uint4*)(Wg + k0);
    uint4 wv1 = *(const uint4*)(Wg + k0 + 8);
    __syncthreads();
    *(uint4*)&Asm[srow][scol] = av0;
    *(uint4*)&Asm[srow][scol + 8] = av1;
    *(uint4*)&Wsm[srow][scol] = wv0;
    *(uint4*)&Wsm[srow][scol + 8] = wv1;
    __syncthreads();
    bfrag a[4], b[4];
#pragma unroll
    for (int mi = 0; mi < 4; ++mi)
      a[mi] = *(const bfrag*)&Asm[wm + mi * 16 + l16][quad * 8];
#pragma unroll
    for (int ni = 0; ni < 4; ++ni)
      b[ni] = *(const bfrag*)&Wsm[wn + ni * 16 + l16][quad * 8];
#pragma unroll
    for (int mi = 0; mi < 4; ++mi)
#pragma unroll
      for (int ni = 0; ni < 4; ++ni)
        acc[mi][ni] = __builtin_amdgcn_mfma_f32_16x16x32_bf16(
            a[mi], b[ni], acc[mi][ni], 0, 0, 0);
  }

#pragma unroll
  for (int mi = 0; mi < 4; ++mi)
#pragma unroll
    for (int ni = 0; ni < 4; ++ni)
#pragma unroll
      for (int r = 0; r < 4; ++r) {
        int row = m0 + wm + mi * 16 + quad * 4 + r;
        int col = n0 + wn + ni * 16 + l16;
        long oi = (long)row * ldc + col;
        float v = acc[mi][ni][r];
        if (EPI == MEPI_STORE_BF16) {
          stf(C, oi, v);
        } else if (EPI == MEPI_GATE) {
          float y = ldf((const bf16*)C, oi);
          float sz = v / (1.f + __expf(-v));
          stf(C, oi, y * sz);
        } else if (EPI == MEPI_BIAS_GELU) {
          v += bias[col];
          v = 0.5f * v * (1.f + erff(v * 0.70710678118654752440f));
          stf(C, oi, v);
        } else if (EPI == MEPI_BIAS_RES) {
          ((float*)C)[oi] = v + bias[col] + res[oi];
        } else if (EPI == MEPI_ACCUM_F32) {
          ((float*)C)[oi] += v;
        }
      }
}

// ---------------------------------------------------------------------------
// MFMA merge: newx(M,DM) = y1 @ W1^T + flip_L(y2) @ W2^T + xres (fp32 out).
// ---------------------------------------------------------------------------
__global__ __launch_bounds__(256) void mmerge_k(
    const bf16* __restrict__ y1, const bf16* __restrict__ y2,
    const bf16* __restrict__ W1, const bf16* __restrict__ W2,
    const float* __restrict__ xres, float* __restrict__ newx) {
  __shared__ u16 Asm[128][40];
  __shared__ u16 Wsm[128][40];
  const int tid = threadIdx.x;
  const int m0 = blockIdx.y * 128;
  const int n0 = blockIdx.x * 128;

  const int srow = tid >> 1;
  const int scol = (tid & 1) * 16;
  int r1 = m0 + srow;
  int tt = r1 & (L_SZ - 1);
  int r2 = (r1 - tt) + (L_SZ - 1 - tt);
  const u16* A1g = (const u16*)y1 + (long)r1 * DIN + scol;
  const u16* A2g = (const u16*)y2 + (long)r2 * DIN + scol;
  const u16* W1g = (const u16*)W1 + (long)(n0 + srow) * DIN + scol;
  const u16* W2g = (const u16*)W2 + (long)(n0 + srow) * DIN + scol;

  const int lane = tid & 63, quad = lane >> 4, l16 = lane & 15;
  const int wid = tid >> 6;
  const int wm = (wid & 1) * 64, wn = (wid >> 1) * 64;

  f32x4 acc[4][4];
#pragma unroll
  for (int i = 0; i < 4; ++i)
#pragma unroll
    for (int j = 0; j < 4; ++j) acc[i][j] = {0.f, 0.f, 0.f, 0.f};

  for (int k0 = 0; k0 < 2 * DIN; k0 += 32) {
    const bool ph2 = (k0 >= DIN);
    const int kk = k0 & (DIN - 1);
    const u16* Ag = ph2 ? A2g : A1g;
    const u16* Wg = ph2 ? W2g : W1g;
    uint4 av0 = *(const uint4*)(Ag + kk);
    uint4 av1 = *(const uint4*)(Ag + kk + 8);
    uint4 wv0 = *(const uint4*)(Wg + kk);
    uint4 wv1 = *(const uint4*)(Wg + kk + 8);
    __syncthreads();
    *(uint4*)&Asm[srow][scol] = av0;
    *(uint4*)&Asm[srow][scol + 8] = av1;
    *(uint4*)&Wsm[srow][scol] = wv0;
    *(uint4*)&Wsm[srow][scol + 8] = wv1;
    __syncthreads();
    bfrag a[4], b[4];
#pragma unroll
    for (int mi = 0; mi < 4; ++mi)
      a[mi] = *(const bfrag*)&Asm[wm + mi * 16 + l16][quad * 8];
#pragma unroll
    for (int ni = 0; ni < 4; ++ni)
      b[ni] = *(const bfrag*)&Wsm[wn + ni * 16 + l16][quad * 8];
#pragma unroll
    for (int mi = 0; mi < 4; ++mi)
#pragma unroll
      for (int ni = 0; ni < 4; ++ni)
        acc[mi][ni] = __builtin_amdgcn_mfma_f32_16x16x32_bf16(
            a[mi], b[ni], acc[mi][ni], 0, 0, 0);
  }

#pragma unroll
  for (int mi = 0; mi < 4; ++mi)
#pragma unroll
    for (int ni = 0; ni < 4; ++ni)
#pragma unroll
      for (int r = 0; r < 4; ++r) {
        int row = m0 + wm + mi * 16 + quad * 4 + r;
        int col = n0 + wn + ni * 16 + l16;
        long oi = (long)row * DM + col;
        newx[oi] = acc[mi][ni][r] + xres[oi];
      }
}

// ---------------------------------------------------------------------------
// Small fp32-compute GEMM (vector ALU): C = A @ W^T.
//   EPI_NONE:          plain (used for xdbl, N=64)
//   EPI_SOFTPLUS_ROW:  softplus(acc + bias[ROW]) (used for dtT: M=d, N=b*t)
// ---------------------------------------------------------------------------
constexpr int EPI_NONE = 0;
constexpr int EPI_SOFTPLUS_ROW = 1;

#define BM 64
#define BN 64
#define BKK 16

template <int EPI, typename TA, typename TO>
__global__ __launch_bounds__(256) void gemm_k(
    const TA* __restrict__ A, int lda,
    const float* __restrict__ W, int ldw,
    TO* __restrict__ C, int ldc,
    const float* __restrict__ bias, int K) {
  __shared__ float As[BKK][BM + 4];
  __shared__ float Ws[BKK][BN + 4];
  const int tid = threadIdx.x;
  const int m0 = blockIdx.y * BM;
  const int n0 = blockIdx.x * BN;
  const int tx = tid & 15;
  const int ty = tid >> 4;
  const int lrow = tid >> 2;
  const int lcol = (tid & 3) * 4;

  const TA* Arow = A + (long)(m0 + lrow) * lda;
  const float* Wrow = W + (long)(n0 + lrow) * ldw;

  float acc[4][4] = {};
  for (int k0 = 0; k0 < K; k0 += BKK) {
    float4 av = ld4f(Arow + k0 + lcol);
    float4 wv = ld4f(Wrow + k0 + lcol);
    As[lcol + 0][lrow] = av.x; As[lcol + 1][lrow] = av.y;
    As[lcol + 2][lrow] = av.z; As[lcol + 3][lrow] = av.w;
    Ws[lcol + 0][lrow] = wv.x; Ws[lcol + 1][lrow] = wv.y;
    Ws[lcol + 2][lrow] = wv.z; Ws[lcol + 3][lrow] = wv.w;
    __syncthreads();
#pragma unroll
    for (int k = 0; k < BKK; ++k) {
      float a[4], b[4];
#pragma unroll
      for (int i = 0; i < 4; ++i) a[i] = As[k][ty * 4 + i];
#pragma unroll
      for (int j = 0; j < 4; ++j) b[j] = Ws[k][tx * 4 + j];
#pragma unroll
      for (int i = 0; i < 4; ++i)
#pragma unroll
        for (int j = 0; j < 4; ++j) acc[i][j] += a[i] * b[j];
    }
    __syncthreads();
  }

#pragma unroll
  for (int i = 0; i < 4; ++i) {
    int r = m0 + ty * 4 + i;
#pragma unroll
    for (int j = 0; j < 4; ++j) {
      int c = n0 + tx * 4 + j;
      float v = acc[i][j];
      if (EPI == EPI_SOFTPLUS_ROW) {
        v += bias[r];
        v = (v > 20.f) ? v : log1pf(__expf(v));
      }
      stf(C, (long)r * ldc + c, v);
    }
  }
}

// ---------------------------------------------------------------------------
// Depthwise causal conv (k=4) + bias + silu. bf16 in/out, fp32 weights.
// ---------------------------------------------------------------------------
__global__ __launch_bounds__(256) void conv_silu_k(
    const bf16* __restrict__ xs, const float* __restrict__ w,
    const float* __restrict__ b, bf16* __restrict__ xc) {
  long idx = (long)blockIdx.x * 256 + threadIdx.x;
  int d = (int)(idx & (DIN - 1));
  long bt = idx >> 10;
  int t = (int)(bt & (L_SZ - 1));
  long base = bt * DIN + d;
  float acc = b[d];
  if (t >= 3) acc += ldf(xs, base - 3L * DIN) * w[d * 4 + 0];
  if (t >= 2) acc += ldf(xs, base - 2L * DIN) * w[d * 4 + 1];
  if (t >= 1) acc += ldf(xs, base - 1L * DIN) * w[d * 4 + 2];
  acc += ldf(xs, base) * w[d * 4 + 3];
  stf(xc, base, acc / (1.f + __expf(-acc)));
}

// ---------------------------------------------------------------------------
// 64x64-tile bf16 transpose: in (MROWS x DIN) -> out (DIN x MROWS).
// ---------------------------------------------------------------------------
__global__ __launch_bounds__(256) void transp_k(const u16* __restrict__ in,
                                                u16* __restrict__ out) {
  __shared__ u16 tile[64][66];
  int c0 = blockIdx.x * 64;   // d
  int r0 = blockIdx.y * 64;   // bt
  int tr = threadIdx.x >> 2;
  int tc = (threadIdx.x & 3) * 16;
  const u16* src = in + (long)(r0 + tr) * DIN + c0 + tc;
  uint4 v0 = *(const uint4*)src;
  uint4 v1 = *(const uint4*)(src + 8);
  u16 tmp[16];
  *(uint4*)tmp = v0;
  *(uint4*)(tmp + 8) = v1;
#pragma unroll
  for (int j = 0; j < 16; ++j) tile[tc + j][tr] = tmp[j];
  __syncthreads();
#pragma unroll
  for (int j = 0; j < 16; ++j) tmp[j] = tile[tr][tc + j];
  u16* dst = out + (long)(c0 + tr) * MROWS + r0 + tc;
  *(uint4*)dst = *(uint4*)tmp;
  *(uint4*)(dst + 8) = *(uint4*)(tmp + 8);
}

// ---------------------------------------------------------------------------
// Extract B/C cols (32..63) of xdbl (MROWS x 64 fp32), transpose to
// bcT (32 x MROWS) bf16. Writes coalesced (bt contiguous across lanes).
// ---------------------------------------------------------------------------
__global__ __launch_bounds__(256) void bct_k(const float* __restrict__ xdbl,
                                             bf16* __restrict__ bcT) {
  int bt = blockIdx.x * 256 + threadIdx.x;
  const float* src = xdbl + (long)bt * 64 + 32;
#pragma unroll
  for (int k = 0; k < 32; ++k)
    stf(bcT, (long)k * MROWS + bt, src[k]);
}

// ---------------------------------------------------------------------------
// Selective scan + skip (u*D). All operands t-contiguous:
//   dtT,uT: (DIN x MROWS) bf16; bcT: (32 x MROWS) bf16 (B rows 0-15, C 16-31).
// Output y UNGATED, normal layout (bt, d), bf16 (gating in mgemm epilogue).
// One 16-lane group per (b,d); lane = state s. Depth-2 vector prefetch:
// per 8 steps, 4 x uint4 loads (vs 32 scalars before).
// ---------------------------------------------------------------------------
__global__ __launch_bounds__(256) void scan_k(
    const u16* __restrict__ dtT, const u16* __restrict__ uT,
    const u16* __restrict__ bcT,
    const float* __restrict__ Alog, const float* __restrict__ Dp,
    bf16* __restrict__ out) {
  int tid = threadIdx.x;
  int s = tid & 15;
  int gi = tid >> 4;
  int blk = blockIdx.x;               // 0..511
  int b = blk >> 6;
  int d = ((blk & 63) << 4) + gi;
  float A = -__expf(Alog[d * DSTATE + s]);
  float Dd = Dp[d];
  float h = 0.f;
  const u16* pdt = dtT + (long)d * MROWS + b * L_SZ;
  const u16* pu = uT + (long)d * MROWS + b * L_SZ;
  const u16* pB = bcT + (long)s * MROWS + b * L_SZ;
  const u16* pC = bcT + (long)(DSTATE + s) * MROWS + b * L_SZ;
  long io = (long)b * L_SZ * DIN + d;

  uint4 dt0 = *(const uint4*)pdt, dt1 = *(const uint4*)(pdt + 8);
  uint4 u0 = *(const uint4*)pu, u1 = *(const uint4*)(pu + 8);
  uint4 B0 = *(const uint4*)pB, B1 = *(const uint4*)(pB + 8);
  uint4 C0 = *(const uint4*)pC, C1 = *(const uint4*)(pC + 8);

  union U8 { uint4 v; u16 a[8]; };
  for (int g = 0; g < L_SZ / 8; ++g) {
    U8 cdt, cu, cB, cC;
    cdt.v = dt0; cu.v = u0; cB.v = B0; cC.v = C0;
    dt0 = dt1; u0 = u1; B0 = B1; C0 = C1;
    if (g + 2 < L_SZ / 8) {
      int off = (g + 2) * 8;
      dt1 = *(const uint4*)(pdt + off);
      u1 = *(const uint4*)(pu + off);
      B1 = *(const uint4*)(pB + off);
      C1 = *(const uint4*)(pC + off);
    }
#pragma unroll
    for (int j = 0; j < 8; ++j) {
      float dtv = b2f(cdt.a[j]);
      float uv = b2f(cu.a[j]);
      float da = __expf(dtv * A);
      h = da * h + (dtv * uv) * b2f(cB.a[j]);
      float p = h * b2f(cC.a[j]);
      p += __shfl_xor(p, 1, 16);
      p += __shfl_xor(p, 2, 16);
      p += __shfl_xor(p, 4, 16);
      p += __shfl_xor(p, 8, 16);
      if (s == 0) stf(out, io + (long)j * DIN, p + Dd * uv);
    }
    io += 8L * DIN;
  }
}

// ---------------------------------------------------------------------------
// LayerNorm over last dim (512). fp32 in; fp32 out + optional bf16 copy.
// ---------------------------------------------------------------------------
__global__ __launch_bounds__(256) void ln_k(
    const float* __restrict__ xin, const float* __restrict__ g,
    const float* __restrict__ bb, float* __restrict__ out,
    bf16* __restrict__ outb) {
  int row = blockIdx.x;
  const float* p = xin + (long)row * DM;
  int tid = threadIdx.x;
  float x0 = p[tid], x1 = p[tid + 256];
  float sum = x0 + x1;
  float sq = x0 * x0 + x1 * x1;
#pragma unroll
  for (int o = 1; o < 64; o <<= 1) {
    sum += __shfl_xor(sum, o, 64);
    sq += __shfl_xor(sq, o, 64);
  }
  __shared__ float ssum[4], ssq[4];
  int wv = tid >> 6;
  if ((tid & 63) == 0) { ssum[wv] = sum; ssq[wv] = sq; }
  __syncthreads();
  sum = ssum[0] + ssum[1] + ssum[2] + ssum[3];
  sq = ssq[0] + ssq[1] + ssq[2] + ssq[3];
  float mean = sum * (1.f / DM);
  float var = sq * (1.f / DM) - mean * mean;
  float rstd = rsqrtf(var + 1e-5f);
  float v0 = (x0 - mean) * rstd * g[tid] + bb[tid];
  float v1 = (x1 - mean) * rstd * g[tid + 256] + bb[tid + 256];
  out[(long)row * DM + tid] = v0;
  out[(long)row * DM + tid + 256] = v1;
  if (outb) {
    stf(outb, (long)row * DM + tid, v0);
    stf(outb, (long)row * DM + tid + 256, v1);
  }
}

// ---------------------------------------------------------------------------
// Orchestration. Workspace 82 MB (proven-safe < 90 MB):
//  xb [0,8): x bf16
//  weights [8,18): in1b(2) in2b(2) o1b(1) o2b(1) c1b(2) c2b(2)
//  P [18,34): xs1 -> xs2 -> uT2 -> xln(fp32)
//  Q [34,50): xc1 -> y1 -> y1 gated -> xln(bf16)
//  R [50,66): dtT1 -> xc2 -> y2 -> y2 gated -> ffn chunks
//  S [66,82): uT1 -> dtT2 -> newx(fp32) -> outacc(fp32)
//  d_out: xdbl fp32 (2 MB @0) + bcT bf16 (0.5 MB @4 MB); overwritten by LN2.
// ---------------------------------------------------------------------------
extern "C" void kernel_launch(void* const* d_in, const int* in_sizes, int n_in,
                              void* d_out, int out_size, void* d_ws, size_t ws_size,
                              hipStream_t stream) {
  const float* x = (const float*)d_in[0];
  const float* in1_w = (const float*)d_in[1];
  const float* conv1_w = (const float*)d_in[2];
  const float* conv1_b = (const float*)d_in[3];
  const float* xp1_w = (const float*)d_in[4];
  const float* dtp1_w = (const float*)d_in[5];
  const float* dtp1_b = (const float*)d_in[6];
  const float* Alog1 = (const float*)d_in[7];
  const float* D1 = (const float*)d_in[8];
  const float* outp1_w = (const float*)d_in[9];
  const float* in2_w = (const float*)d_in[10];
  const float* conv2_w = (const float*)d_in[11];
  const float* conv2_b = (const float*)d_in[12];
  const float* xp2_w = (const float*)d_in[13];
  const float* dtp2_w = (const float*)d_in[14];
  const float* dtp2_b = (const float*)d_in[15];
  const float* Alog2 = (const float*)d_in[16];
  const float* D2 = (const float*)d_in[17];
  const float* outp2_w = (const float*)d_in[18];
  const float* c1_w = (const float*)d_in[19];
  const float* c1_b = (const float*)d_in[20];
  const float* c2_w = (const float*)d_in[21];
  const float* c2_b = (const float*)d_in[22];
  const float* ln1_g = (const float*)d_in[23];
  const float* ln1_b = (const float*)d_in[24];
  const float* ln2_g = (const float*)d_in[25];
  const float* ln2_b = (const float*)d_in[26];

  char* wsb = (char*)d_ws;
  const long MB = 1024L * 1024;
  bf16* xb = (bf16*)(wsb);
  bf16* wbb = (bf16*)(wsb + 8 * MB);
  bf16* in1b = wbb;
  bf16* in2b = wbb + 1048576L;
  bf16* o1b = wbb + 2097152L;
  bf16* o2b = wbb + 2621440L;
  bf16* c1b = wbb + 3145728L;
  bf16* c2b = wbb + 4194304L;
  bf16* P = (bf16*)(wsb + 18 * MB);
  bf16* Q = (bf16*)(wsb + 34 * MB);
  bf16* R = (bf16*)(wsb + 50 * MB);
  bf16* S = (bf16*)(wsb + 66 * MB);
  float* Pf = (float*)P;
  float* Sf = (float*)S;
  float* xdbl = (float*)d_out;               // 512K fp32 (2 MB)
  bf16* bcT = (bf16*)((char*)d_out + 4 * MB);  // 256K bf16 (0.5 MB)

  dim3 blk(256);
  dim3 gP(DIN / 128, MROWS / 128);
  dim3 gM(DM / 128, MROWS / 128);
  dim3 gT(DIN / 64, MROWS / 64);
  dim3 gDT(MROWS / BN, DIN / BM);

  // ---- conversions ----
  cvt_k<<<(MROWS * DM) / 256, blk, 0, stream>>>(x, xb, MROWS * DM);
  cvt_k<<<(2 * DIN * DM) / 256, blk, 0, stream>>>(in1_w, in1b, 2 * DIN * DM);
  cvt_k<<<(2 * DIN * DM) / 256, blk, 0, stream>>>(in2_w, in2b, 2 * DIN * DM);
  cvt_k<<<(DM * DIN) / 256, blk, 0, stream>>>(outp1_w, o1b, DM * DIN);
  cvt_k<<<(DM * DIN) / 256, blk, 0, stream>>>(outp2_w, o2b, DM * DIN);
  cvt_k<<<(DFF * DM) / 256, blk, 0, stream>>>(c1_w, c1b, DFF * DM);
  cvt_k<<<(DM * DFF) / 256, blk, 0, stream>>>(c2_w, c2b, DM * DFF);

  // ---- direction 1 ----
  mgemm_k<MEPI_STORE_BF16, false, bf16><<<gP, blk, 0, stream>>>(
      xb, DM, in1b, DM, P, DIN, nullptr, nullptr, DM);                   // xs1
  conv_silu_k<<<(MROWS * DIN) / 256, blk, 0, stream>>>(P, conv1_w, conv1_b, Q);
  gemm_k<EPI_NONE, bf16, float><<<dim3(1, MROWS / BM), blk, 0, stream>>>(
      Q, DIN, xp1_w, DIN, xdbl, 64, nullptr, DIN);                       // xdbl1
  gemm_k<EPI_SOFTPLUS_ROW, float, bf16><<<gDT, blk, 0, stream>>>(
      dtp1_w, DTRANK, xdbl, 64, R, MROWS, dtp1_b, DTRANK);               // dtT1
  transp_k<<<gT, blk, 0, stream>>>((const u16*)Q, (u16*)S);              // uT1
  bct_k<<<MROWS / 256, blk, 0, stream>>>(xdbl, bcT);                     // bcT1
  scan_k<<<B_SZ * (DIN / 16), blk, 0, stream>>>(
      (const u16*)R, (const u16*)S, (const u16*)bcT, Alog1, D1, Q);      // y1
  mgemm_k<MEPI_GATE, false, bf16><<<gP, blk, 0, stream>>>(
      xb, DM, in1b + (long)DIN * DM, DM, Q, DIN, nullptr, nullptr, DM);  // gate y1

  // ---- direction 2 (flipped sequence) ----
  mgemm_k<MEPI_STORE_BF16, true, bf16><<<gP, blk, 0, stream>>>(
      xb, DM, in2b, DM, P, DIN, nullptr, nullptr, DM);                   // xs2
  conv_silu_k<<<(MROWS * DIN) / 256, blk, 0, stream>>>(P, conv2_w, conv2_b, R);
  gemm_k<EPI_NONE, bf16, float><<<dim3(1, MROWS / BM), blk, 0, stream>>>(
      R, DIN, xp2_w, DIN, xdbl, 64, nullptr, DIN);                       // xdbl2
  gemm_k<EPI_SOFTPLUS_ROW, float, bf16><<<gDT, blk, 0, stream>>>(
      dtp2_w, DTRANK, xdbl, 64, S, MROWS, dtp2_b, DTRANK);               // dtT2
  transp_k<<<gT, blk, 0, stream>>>((const u16*)R, (u16*)P);              // uT2
  bct_k<<<MROWS / 256, blk, 0, stream>>>(xdbl, bcT);                     // bcT2
  scan_k<<<B_SZ * (DIN / 16), blk, 0, stream>>>(
      (const u16*)S, (const u16*)P, (const u16*)bcT, Alog2, D2, R);      // y2
  mgemm_k<MEPI_GATE, true, bf16><<<gP, blk, 0, stream>>>(
      xb, DM, in2b + (long)DIN * DM, DM, R, DIN, nullptr, nullptr, DM);  // gate y2

  // ---- merge: newx = y1@W1^T + flip(y2)@W2^T + x ----
  mmerge_k<<<gM, blk, 0, stream>>>(Q, R, o1b, o2b, x, Sf);

  // ---- LN1 (fp32 -> P, bf16 copy -> Q) ----
  ln_k<<<MROWS, blk, 0, stream>>>(Sf, ln1_g, ln1_b, Pf, Q);

  // ---- FFN, 2 chunks of 1024 over DFF ----
  mgemm_k<MEPI_BIAS_GELU, false, bf16><<<gP, blk, 0, stream>>>(
      Q, DM, c1b, DM, R, 1024, c1_b, nullptr, DM);
  mgemm_k<MEPI_BIAS_RES, false, float><<<gM, blk, 0, stream>>>(
      R, 1024, c2b, DFF, Sf, DM, c2_b, Pf, 1024);
  mgemm_k<MEPI_BIAS_GELU, false, bf16><<<gP, blk, 0, stream>>>(
      Q, DM, c1b + 1024L * DM, DM, R, 1024, c1_b + 1024, nullptr, DM);
  mgemm_k<MEPI_ACCUM_F32, false, float><<<gM, blk, 0, stream>>>(
      R, 1024, c2b + 1024, DFF, Sf, DM, nullptr, nullptr, 1024);

  // ---- LN2 -> fp32 out (overwrites xdbl/bcT scratch) ----
  ln_k<<<MROWS, blk, 0, stream>>>(Sf, ln2_g, ln2_b, (float*)d_out, nullptr);
}

// Round 10
// 954.659 us; speedup vs baseline: 3.4168x; 1.1584x over previous
//
#include <hip/hip_runtime.h>
#include <hip/hip_bf16.h>
#include <math.h>

// ---------------------------------------------------------------------------
// Problem constants
// ---------------------------------------------------------------------------
#define B_SZ 8
#define L_SZ 1024
#define DM 512          // d_model
#define DFF 2048        // d_ff
#define DIN 1024        // expand * d_model
#define DSTATE 16
#define DTRANK 32
#define MROWS (B_SZ * L_SZ)   // 8192

typedef __hip_bfloat16 bf16;
typedef unsigned short u16;
using f32x4 = __attribute__((ext_vector_type(4))) float;
using bfrag = __attribute__((ext_vector_type(8))) short;   // 8 bf16 = 4 VGPR

__device__ inline float ldf(const float* p, long i) { return p[i]; }
__device__ inline float ldf(const bf16* p, long i) {
  return __uint_as_float((unsigned)((const u16*)p)[i] << 16);
}
__device__ inline void stf(float* p, long i, float v) { p[i] = v; }
__device__ inline void stf(bf16* p, long i, float v) { p[i] = __float2bfloat16(v); }
__device__ inline float b2f(u16 x) {
  return __uint_as_float((unsigned)x << 16);
}
__device__ inline float4 ld4f(const float* p) { return *(const float4*)p; }
__device__ inline float4 ld4f(const bf16* p) {
  ushort4 u = *(const ushort4*)p;
  float4 v;
  v.x = b2f(u.x); v.y = b2f(u.y); v.z = b2f(u.z); v.w = b2f(u.w);
  return v;
}

// DPP rotation-butterfly add within a 16-lane row: all VALU, no LGKM waits.
// CTRL = 0x120 + n  -> row_ror:n (rotate within the 16-lane DPP row).
template <int CTRL>
__device__ inline float dpp_ror_add(float x) {
  int r = __builtin_amdgcn_update_dpp(0, __float_as_int(x), CTRL, 0xf, 0xf, true);
  return x + __int_as_float(r);
}
__device__ inline float row16_sum(float x) {
  x = dpp_ror_add<0x128>(x);  // ror 8
  x = dpp_ror_add<0x124>(x);  // ror 4
  x = dpp_ror_add<0x122>(x);  // ror 2
  x = dpp_ror_add<0x121>(x);  // ror 1
  return x;                   // every lane of the row holds the 16-lane sum
}

// ---------------------------------------------------------------------------
// fp32 -> bf16 convert
// ---------------------------------------------------------------------------
__global__ __launch_bounds__(256) void cvt_k(const float* __restrict__ s,
                                             bf16* __restrict__ d, int n) {
  int i = blockIdx.x * 256 + threadIdx.x;
  if (i < n) d[i] = __float2bfloat16(s[i]);
}

// ---------------------------------------------------------------------------
// bf16 MFMA GEMM: C(M,N) = A(M,K) @ W(N,K)^T, fp32 accumulate.
// 128x128 tile, BK=32, 4 waves, each 64x64 via 4x4 v_mfma_f32_16x16x32_bf16.
// ---------------------------------------------------------------------------
constexpr int MEPI_STORE_BF16 = 0;
constexpr int MEPI_GATE = 1;        // C[oi] = C[oi] * silu(acc), bf16 in-place
constexpr int MEPI_BIAS_GELU = 2;   // bf16 out
constexpr int MEPI_BIAS_RES = 3;    // fp32 out = acc + bias + res
constexpr int MEPI_ACCUM_F32 = 4;   // fp32 C += acc

template <int EPI, bool FLIPA, typename TO>
__global__ __launch_bounds__(256) void mgemm_k(
    const bf16* __restrict__ Ab, int lda,
    const bf16* __restrict__ Wb, int ldw,
    TO* __restrict__ C, int ldc,
    const float* __restrict__ bias,
    const float* __restrict__ res,
    int K) {
  __shared__ u16 Asm[128][40];
  __shared__ u16 Wsm[128][40];
  const int tid = threadIdx.x;
  const int m0 = blockIdx.y * 128;
  const int n0 = blockIdx.x * 128;

  const int srow = tid >> 1;
  const int scol = (tid & 1) * 16;
  int ar = m0 + srow;
  if (FLIPA) { int t = ar & (L_SZ - 1); ar = (ar - t) + (L_SZ - 1 - t); }
  const u16* Ag = (const u16*)Ab + (long)ar * lda + scol;
  const u16* Wg = (const u16*)Wb + (long)(n0 + srow) * ldw + scol;

  const int lane = tid & 63, quad = lane >> 4, l16 = lane & 15;
  const int wid = tid >> 6;
  const int wm = (wid & 1) * 64, wn = (wid >> 1) * 64;

  f32x4 acc[4][4];
#pragma unroll
  for (int i = 0; i < 4; ++i)
#pragma unroll
    for (int j = 0; j < 4; ++j) acc[i][j] = {0.f, 0.f, 0.f, 0.f};

  for (int k0 = 0; k0 < K; k0 += 32) {
    uint4 av0 = *(const uint4*)(Ag + k0);
    uint4 av1 = *(const uint4*)(Ag + k0 + 8);
    uint4 wv0 = *(const uint4*)(Wg + k0);
    uint4 wv1 = *(const uint4*)(Wg + k0 + 8);
    __syncthreads();
    *(uint4*)&Asm[srow][scol] = av0;
    *(uint4*)&Asm[srow][scol + 8] = av1;
    *(uint4*)&Wsm[srow][scol] = wv0;
    *(uint4*)&Wsm[srow][scol + 8] = wv1;
    __syncthreads();
    bfrag a[4], b[4];
#pragma unroll
    for (int mi = 0; mi < 4; ++mi)
      a[mi] = *(const bfrag*)&Asm[wm + mi * 16 + l16][quad * 8];
#pragma unroll
    for (int ni = 0; ni < 4; ++ni)
      b[ni] = *(const bfrag*)&Wsm[wn + ni * 16 + l16][quad * 8];
#pragma unroll
    for (int mi = 0; mi < 4; ++mi)
#pragma unroll
      for (int ni = 0; ni < 4; ++ni)
        acc[mi][ni] = __builtin_amdgcn_mfma_f32_16x16x32_bf16(
            a[mi], b[ni], acc[mi][ni], 0, 0, 0);
  }

#pragma unroll
  for (int mi = 0; mi < 4; ++mi)
#pragma unroll
    for (int ni = 0; ni < 4; ++ni)
#pragma unroll
      for (int r = 0; r < 4; ++r) {
        int row = m0 + wm + mi * 16 + quad * 4 + r;
        int col = n0 + wn + ni * 16 + l16;
        long oi = (long)row * ldc + col;
        float v = acc[mi][ni][r];
        if (EPI == MEPI_STORE_BF16) {
          stf(C, oi, v);
        } else if (EPI == MEPI_GATE) {
          float y = ldf((const bf16*)C, oi);
          float sz = v / (1.f + __expf(-v));
          stf(C, oi, y * sz);
        } else if (EPI == MEPI_BIAS_GELU) {
          v += bias[col];
          v = 0.5f * v * (1.f + erff(v * 0.70710678118654752440f));
          stf(C, oi, v);
        } else if (EPI == MEPI_BIAS_RES) {
          ((float*)C)[oi] = v + bias[col] + res[oi];
        } else if (EPI == MEPI_ACCUM_F32) {
          ((float*)C)[oi] += v;
        }
      }
}

// ---------------------------------------------------------------------------
// MFMA merge: newx(M,DM) = y1 @ W1^T + flip_L(y2) @ W2^T + xres (fp32 out).
// ---------------------------------------------------------------------------
__global__ __launch_bounds__(256) void mmerge_k(
    const bf16* __restrict__ y1, const bf16* __restrict__ y2,
    const bf16* __restrict__ W1, const bf16* __restrict__ W2,
    const float* __restrict__ xres, float* __restrict__ newx) {
  __shared__ u16 Asm[128][40];
  __shared__ u16 Wsm[128][40];
  const int tid = threadIdx.x;
  const int m0 = blockIdx.y * 128;
  const int n0 = blockIdx.x * 128;

  const int srow = tid >> 1;
  const int scol = (tid & 1) * 16;
  int r1 = m0 + srow;
  int tt = r1 & (L_SZ - 1);
  int r2 = (r1 - tt) + (L_SZ - 1 - tt);
  const u16* A1g = (const u16*)y1 + (long)r1 * DIN + scol;
  const u16* A2g = (const u16*)y2 + (long)r2 * DIN + scol;
  const u16* W1g = (const u16*)W1 + (long)(n0 + srow) * DIN + scol;
  const u16* W2g = (const u16*)W2 + (long)(n0 + srow) * DIN + scol;

  const int lane = tid & 63, quad = lane >> 4, l16 = lane & 15;
  const int wid = tid >> 6;
  const int wm = (wid & 1) * 64, wn = (wid >> 1) * 64;

  f32x4 acc[4][4];
#pragma unroll
  for (int i = 0; i < 4; ++i)
#pragma unroll
    for (int j = 0; j < 4; ++j) acc[i][j] = {0.f, 0.f, 0.f, 0.f};

  for (int k0 = 0; k0 < 2 * DIN; k0 += 32) {
    const bool ph2 = (k0 >= DIN);
    const int kk = k0 & (DIN - 1);
    const u16* Ag = ph2 ? A2g : A1g;
    const u16* Wg = ph2 ? W2g : W1g;
    uint4 av0 = *(const uint4*)(Ag + kk);
    uint4 av1 = *(const uint4*)(Ag + kk + 8);
    uint4 wv0 = *(const uint4*)(Wg + kk);
    uint4 wv1 = *(const uint4*)(Wg + kk + 8);
    __syncthreads();
    *(uint4*)&Asm[srow][scol] = av0;
    *(uint4*)&Asm[srow][scol + 8] = av1;
    *(uint4*)&Wsm[srow][scol] = wv0;
    *(uint4*)&Wsm[srow][scol + 8] = wv1;
    __syncthreads();
    bfrag a[4], b[4];
#pragma unroll
    for (int mi = 0; mi < 4; ++mi)
      a[mi] = *(const bfrag*)&Asm[wm + mi * 16 + l16][quad * 8];
#pragma unroll
    for (int ni = 0; ni < 4; ++ni)
      b[ni] = *(const bfrag*)&Wsm[wn + ni * 16 + l16][quad * 8];
#pragma unroll
    for (int mi = 0; mi < 4; ++mi)
#pragma unroll
      for (int ni = 0; ni < 4; ++ni)
        acc[mi][ni] = __builtin_amdgcn_mfma_f32_16x16x32_bf16(
            a[mi], b[ni], acc[mi][ni], 0, 0, 0);
  }

#pragma unroll
  for (int mi = 0; mi < 4; ++mi)
#pragma unroll
    for (int ni = 0; ni < 4; ++ni)
#pragma unroll
      for (int r = 0; r < 4; ++r) {
        int row = m0 + wm + mi * 16 + quad * 4 + r;
        int col = n0 + wn + ni * 16 + l16;
        long oi = (long)row * DM + col;
        newx[oi] = acc[mi][ni][r] + xres[oi];
      }
}

// ---------------------------------------------------------------------------
// Small fp32-compute GEMM (vector ALU): C = A @ W^T.
//   EPI_NONE:          plain (used for xdbl, N=64)
//   EPI_SOFTPLUS_ROW:  softplus(acc + bias[ROW]) (used for dtT: M=d, N=b*t)
// ---------------------------------------------------------------------------
constexpr int EPI_NONE = 0;
constexpr int EPI_SOFTPLUS_ROW = 1;

#define BM 64
#define BN 64
#define BKK 16

template <int EPI, typename TA, typename TO>
__global__ __launch_bounds__(256) void gemm_k(
    const TA* __restrict__ A, int lda,
    const float* __restrict__ W, int ldw,
    TO* __restrict__ C, int ldc,
    const float* __restrict__ bias, int K) {
  __shared__ float As[BKK][BM + 4];
  __shared__ float Ws[BKK][BN + 4];
  const int tid = threadIdx.x;
  const int m0 = blockIdx.y * BM;
  const int n0 = blockIdx.x * BN;
  const int tx = tid & 15;
  const int ty = tid >> 4;
  const int lrow = tid >> 2;
  const int lcol = (tid & 3) * 4;

  const TA* Arow = A + (long)(m0 + lrow) * lda;
  const float* Wrow = W + (long)(n0 + lrow) * ldw;

  float acc[4][4] = {};
  for (int k0 = 0; k0 < K; k0 += BKK) {
    float4 av = ld4f(Arow + k0 + lcol);
    float4 wv = ld4f(Wrow + k0 + lcol);
    As[lcol + 0][lrow] = av.x; As[lcol + 1][lrow] = av.y;
    As[lcol + 2][lrow] = av.z; As[lcol + 3][lrow] = av.w;
    Ws[lcol + 0][lrow] = wv.x; Ws[lcol + 1][lrow] = wv.y;
    Ws[lcol + 2][lrow] = wv.z; Ws[lcol + 3][lrow] = wv.w;
    __syncthreads();
#pragma unroll
    for (int k = 0; k < BKK; ++k) {
      float a[4], b[4];
#pragma unroll
      for (int i = 0; i < 4; ++i) a[i] = As[k][ty * 4 + i];
#pragma unroll
      for (int j = 0; j < 4; ++j) b[j] = Ws[k][tx * 4 + j];
#pragma unroll
      for (int i = 0; i < 4; ++i)
#pragma unroll
        for (int j = 0; j < 4; ++j) acc[i][j] += a[i] * b[j];
    }
    __syncthreads();
  }

#pragma unroll
  for (int i = 0; i < 4; ++i) {
    int r = m0 + ty * 4 + i;
#pragma unroll
    for (int j = 0; j < 4; ++j) {
      int c = n0 + tx * 4 + j;
      float v = acc[i][j];
      if (EPI == EPI_SOFTPLUS_ROW) {
        v += bias[r];
        v = (v > 20.f) ? v : log1pf(__expf(v));
      }
      stf(C, (long)r * ldc + c, v);
    }
  }
}

// ---------------------------------------------------------------------------
// Depthwise causal conv (k=4) + bias + silu. bf16 in/out, fp32 weights.
// ---------------------------------------------------------------------------
__global__ __launch_bounds__(256) void conv_silu_k(
    const bf16* __restrict__ xs, const float* __restrict__ w,
    const float* __restrict__ b, bf16* __restrict__ xc) {
  long idx = (long)blockIdx.x * 256 + threadIdx.x;
  int d = (int)(idx & (DIN - 1));
  long bt = idx >> 10;
  int t = (int)(bt & (L_SZ - 1));
  long base = bt * DIN + d;
  float acc = b[d];
  if (t >= 3) acc += ldf(xs, base - 3L * DIN) * w[d * 4 + 0];
  if (t >= 2) acc += ldf(xs, base - 2L * DIN) * w[d * 4 + 1];
  if (t >= 1) acc += ldf(xs, base - 1L * DIN) * w[d * 4 + 2];
  acc += ldf(xs, base) * w[d * 4 + 3];
  stf(xc, base, acc / (1.f + __expf(-acc)));
}

// ---------------------------------------------------------------------------
// 64x64-tile bf16 transpose: in (MROWS x DIN) -> out (DIN x MROWS).
// ---------------------------------------------------------------------------
__global__ __launch_bounds__(256) void transp_k(const u16* __restrict__ in,
                                                u16* __restrict__ out) {
  __shared__ u16 tile[64][66];
  int c0 = blockIdx.x * 64;   // d
  int r0 = blockIdx.y * 64;   // bt
  int tr = threadIdx.x >> 2;
  int tc = (threadIdx.x & 3) * 16;
  const u16* src = in + (long)(r0 + tr) * DIN + c0 + tc;
  uint4 v0 = *(const uint4*)src;
  uint4 v1 = *(const uint4*)(src + 8);
  u16 tmp[16];
  *(uint4*)tmp = v0;
  *(uint4*)(tmp + 8) = v1;
#pragma unroll
  for (int j = 0; j < 16; ++j) tile[tc + j][tr] = tmp[j];
  __syncthreads();
#pragma unroll
  for (int j = 0; j < 16; ++j) tmp[j] = tile[tr][tc + j];
  u16* dst = out + (long)(c0 + tr) * MROWS + r0 + tc;
  *(uint4*)dst = *(uint4*)tmp;
  *(uint4*)(dst + 8) = *(uint4*)(tmp + 8);
}

// ---------------------------------------------------------------------------
// Extract B/C cols (32..63) of xdbl (MROWS x 64 fp32), transpose to
// bcT (32 x MROWS) bf16. Writes coalesced (bt contiguous across lanes).
// ---------------------------------------------------------------------------
__global__ __launch_bounds__(256) void bct_k(const float* __restrict__ xdbl,
                                             bf16* __restrict__ bcT) {
  int bt = blockIdx.x * 256 + threadIdx.x;
  const float* src = xdbl + (long)bt * 64 + 32;
#pragma unroll
  for (int k = 0; k < 32; ++k)
    stf(bcT, (long)k * MROWS + bt, src[k]);
}

// ---------------------------------------------------------------------------
// Selective scan + skip (u*D). All operands t-contiguous:
//   dtT,uT: (DIN x MROWS) bf16; bcT: (32 x MROWS) bf16 (B rows 0-15, C 16-31).
// Output y UNGATED, normal layout (bt, d), bf16 (gating in mgemm epilogue).
// One 16-lane group per (b,d); lane = state s. Depth-2 vector prefetch;
// 16-lane reduce via DPP row_ror butterfly (pure VALU, no lgkm waits).
// ---------------------------------------------------------------------------
__global__ __launch_bounds__(256) void scan_k(
    const u16* __restrict__ dtT, const u16* __restrict__ uT,
    const u16* __restrict__ bcT,
    const float* __restrict__ Alog, const float* __restrict__ Dp,
    bf16* __restrict__ out) {
  int tid = threadIdx.x;
  int s = tid & 15;
  int gi = tid >> 4;
  int blk = blockIdx.x;               // 0..511
  int b = blk >> 6;
  int d = ((blk & 63) << 4) + gi;
  float A = -__expf(Alog[d * DSTATE + s]);
  float Dd = Dp[d];
  float h = 0.f;
  const u16* pdt = dtT + (long)d * MROWS + b * L_SZ;
  const u16* pu = uT + (long)d * MROWS + b * L_SZ;
  const u16* pB = bcT + (long)s * MROWS + b * L_SZ;
  const u16* pC = bcT + (long)(DSTATE + s) * MROWS + b * L_SZ;
  long io = (long)b * L_SZ * DIN + d;

  uint4 dt0 = *(const uint4*)pdt, dt1 = *(const uint4*)(pdt + 8);
  uint4 u0 = *(const uint4*)pu, u1 = *(const uint4*)(pu + 8);
  uint4 B0 = *(const uint4*)pB, B1 = *(const uint4*)(pB + 8);
  uint4 C0 = *(const uint4*)pC, C1 = *(const uint4*)(pC + 8);

  union U8 { uint4 v; u16 a[8]; };
  for (int g = 0; g < L_SZ / 8; ++g) {
    U8 cdt, cu, cB, cC;
    cdt.v = dt0; cu.v = u0; cB.v = B0; cC.v = C0;
    dt0 = dt1; u0 = u1; B0 = B1; C0 = C1;
    if (g + 2 < L_SZ / 8) {
      int off = (g + 2) * 8;
      dt1 = *(const uint4*)(pdt + off);
      u1 = *(const uint4*)(pu + off);
      B1 = *(const uint4*)(pB + off);
      C1 = *(const uint4*)(pC + off);
    }
#pragma unroll
    for (int j = 0; j < 8; ++j) {
      float dtv = b2f(cdt.a[j]);
      float uv = b2f(cu.a[j]);
      float da = __expf(dtv * A);
      h = da * h + (dtv * uv) * b2f(cB.a[j]);
      float p = row16_sum(h * b2f(cC.a[j]));
      if (s == 0) stf(out, io + (long)j * DIN, p + Dd * uv);
    }
    io += 8L * DIN;
  }
}

// ---------------------------------------------------------------------------
// LayerNorm over last dim (512). fp32 in; fp32 out + optional bf16 copy.
// ---------------------------------------------------------------------------
__global__ __launch_bounds__(256) void ln_k(
    const float* __restrict__ xin, const float* __restrict__ g,
    const float* __restrict__ bb, float* __restrict__ out,
    bf16* __restrict__ outb) {
  int row = blockIdx.x;
  const float* p = xin + (long)row * DM;
  int tid = threadIdx.x;
  float x0 = p[tid], x1 = p[tid + 256];
  float sum = x0 + x1;
  float sq = x0 * x0 + x1 * x1;
#pragma unroll
  for (int o = 1; o < 64; o <<= 1) {
    sum += __shfl_xor(sum, o, 64);
    sq += __shfl_xor(sq, o, 64);
  }
  __shared__ float ssum[4], ssq[4];
  int wv = tid >> 6;
  if ((tid & 63) == 0) { ssum[wv] = sum; ssq[wv] = sq; }
  __syncthreads();
  sum = ssum[0] + ssum[1] + ssum[2] + ssum[3];
  sq = ssq[0] + ssq[1] + ssq[2] + ssq[3];
  float mean = sum * (1.f / DM);
  float var = sq * (1.f / DM) - mean * mean;
  float rstd = rsqrtf(var + 1e-5f);
  float v0 = (x0 - mean) * rstd * g[tid] + bb[tid];
  float v1 = (x1 - mean) * rstd * g[tid + 256] + bb[tid + 256];
  out[(long)row * DM + tid] = v0;
  out[(long)row * DM + tid + 256] = v1;
  if (outb) {
    stf(outb, (long)row * DM + tid, v0);
    stf(outb, (long)row * DM + tid + 256, v1);
  }
}

// ---------------------------------------------------------------------------
// Orchestration. Workspace 82 MB (proven-safe < 90 MB):
//  xb [0,8): x bf16
//  weights [8,18): in1b(2) in2b(2) o1b(1) o2b(1) c1b(2) c2b(2)
//  P [18,34): xs1 -> xs2 -> uT2 -> xln(fp32)
//  Q [34,50): xc1 -> y1 -> y1 gated -> xln(bf16)
//  R [50,66): dtT1 -> xc2 -> y2 -> y2 gated -> ffn chunks
//  S [66,82): uT1 -> dtT2 -> newx(fp32) -> outacc(fp32)
//  d_out: xdbl fp32 (2 MB @0) + bcT bf16 (0.5 MB @4 MB); overwritten by LN2.
// ---------------------------------------------------------------------------
extern "C" void kernel_launch(void* const* d_in, const int* in_sizes, int n_in,
                              void* d_out, int out_size, void* d_ws, size_t ws_size,
                              hipStream_t stream) {
  const float* x = (const float*)d_in[0];
  const float* in1_w = (const float*)d_in[1];
  const float* conv1_w = (const float*)d_in[2];
  const float* conv1_b = (const float*)d_in[3];
  const float* xp1_w = (const float*)d_in[4];
  const float* dtp1_w = (const float*)d_in[5];
  const float* dtp1_b = (const float*)d_in[6];
  const float* Alog1 = (const float*)d_in[7];
  const float* D1 = (const float*)d_in[8];
  const float* outp1_w = (const float*)d_in[9];
  const float* in2_w = (const float*)d_in[10];
  const float* conv2_w = (const float*)d_in[11];
  const float* conv2_b = (const float*)d_in[12];
  const float* xp2_w = (const float*)d_in[13];
  const float* dtp2_w = (const float*)d_in[14];
  const float* dtp2_b = (const float*)d_in[15];
  const float* Alog2 = (const float*)d_in[16];
  const float* D2 = (const float*)d_in[17];
  const float* outp2_w = (const float*)d_in[18];
  const float* c1_w = (const float*)d_in[19];
  const float* c1_b = (const float*)d_in[20];
  const float* c2_w = (const float*)d_in[21];
  const float* c2_b = (const float*)d_in[22];
  const float* ln1_g = (const float*)d_in[23];
  const float* ln1_b = (const float*)d_in[24];
  const float* ln2_g = (const float*)d_in[25];
  const float* ln2_b = (const float*)d_in[26];

  char* wsb = (char*)d_ws;
  const long MB = 1024L * 1024;
  bf16* xb = (bf16*)(wsb);
  bf16* wbb = (bf16*)(wsb + 8 * MB);
  bf16* in1b = wbb;
  bf16* in2b = wbb + 1048576L;
  bf16* o1b = wbb + 2097152L;
  bf16* o2b = wbb + 2621440L;
  bf16* c1b = wbb + 3145728L;
  bf16* c2b = wbb + 4194304L;
  bf16* P = (bf16*)(wsb + 18 * MB);
  bf16* Q = (bf16*)(wsb + 34 * MB);
  bf16* R = (bf16*)(wsb + 50 * MB);
  bf16* S = (bf16*)(wsb + 66 * MB);
  float* Pf = (float*)P;
  float* Sf = (float*)S;
  float* xdbl = (float*)d_out;               // 512K fp32 (2 MB)
  bf16* bcT = (bf16*)((char*)d_out + 4 * MB);  // 256K bf16 (0.5 MB)

  dim3 blk(256);
  dim3 gP(DIN / 128, MROWS / 128);
  dim3 gM(DM / 128, MROWS / 128);
  dim3 gT(DIN / 64, MROWS / 64);
  dim3 gDT(MROWS / BN, DIN / BM);

  // ---- conversions ----
  cvt_k<<<(MROWS * DM) / 256, blk, 0, stream>>>(x, xb, MROWS * DM);
  cvt_k<<<(2 * DIN * DM) / 256, blk, 0, stream>>>(in1_w, in1b, 2 * DIN * DM);
  cvt_k<<<(2 * DIN * DM) / 256, blk, 0, stream>>>(in2_w, in2b, 2 * DIN * DM);
  cvt_k<<<(DM * DIN) / 256, blk, 0, stream>>>(outp1_w, o1b, DM * DIN);
  cvt_k<<<(DM * DIN) / 256, blk, 0, stream>>>(outp2_w, o2b, DM * DIN);
  cvt_k<<<(DFF * DM) / 256, blk, 0, stream>>>(c1_w, c1b, DFF * DM);
  cvt_k<<<(DM * DFF) / 256, blk, 0, stream>>>(c2_w, c2b, DM * DFF);

  // ---- direction 1 ----
  mgemm_k<MEPI_STORE_BF16, false, bf16><<<gP, blk, 0, stream>>>(
      xb, DM, in1b, DM, P, DIN, nullptr, nullptr, DM);                   // xs1
  conv_silu_k<<<(MROWS * DIN) / 256, blk, 0, stream>>>(P, conv1_w, conv1_b, Q);
  gemm_k<EPI_NONE, bf16, float><<<dim3(1, MROWS / BM), blk, 0, stream>>>(
      Q, DIN, xp1_w, DIN, xdbl, 64, nullptr, DIN);                       // xdbl1
  gemm_k<EPI_SOFTPLUS_ROW, float, bf16><<<gDT, blk, 0, stream>>>(
      dtp1_w, DTRANK, xdbl, 64, R, MROWS, dtp1_b, DTRANK);               // dtT1
  transp_k<<<gT, blk, 0, stream>>>((const u16*)Q, (u16*)S);              // uT1
  bct_k<<<MROWS / 256, blk, 0, stream>>>(xdbl, bcT);                     // bcT1
  scan_k<<<B_SZ * (DIN / 16), blk, 0, stream>>>(
      (const u16*)R, (const u16*)S, (const u16*)bcT, Alog1, D1, Q);      // y1
  mgemm_k<MEPI_GATE, false, bf16><<<gP, blk, 0, stream>>>(
      xb, DM, in1b + (long)DIN * DM, DM, Q, DIN, nullptr, nullptr, DM);  // gate y1

  // ---- direction 2 (flipped sequence) ----
  mgemm_k<MEPI_STORE_BF16, true, bf16><<<gP, blk, 0, stream>>>(
      xb, DM, in2b, DM, P, DIN, nullptr, nullptr, DM);                   // xs2
  conv_silu_k<<<(MROWS * DIN) / 256, blk, 0, stream>>>(P, conv2_w, conv2_b, R);
  gemm_k<EPI_NONE, bf16, float><<<dim3(1, MROWS / BM), blk, 0, stream>>>(
      R, DIN, xp2_w, DIN, xdbl, 64, nullptr, DIN);                       // xdbl2
  gemm_k<EPI_SOFTPLUS_ROW, float, bf16><<<gDT, blk, 0, stream>>>(
      dtp2_w, DTRANK, xdbl, 64, S, MROWS, dtp2_b, DTRANK);               // dtT2
  transp_k<<<gT, blk, 0, stream>>>((const u16*)R, (u16*)P);              // uT2
  bct_k<<<MROWS / 256, blk, 0, stream>>>(xdbl, bcT);                     // bcT2
  scan_k<<<B_SZ * (DIN / 16), blk, 0, stream>>>(
      (const u16*)S, (const u16*)P, (const u16*)bcT, Alog2, D2, R);      // y2
  mgemm_k<MEPI_GATE, true, bf16><<<gP, blk, 0, stream>>>(
      xb, DM, in2b + (long)DIN * DM, DM, R, DIN, nullptr, nullptr, DM);  // gate y2

  // ---- merge: newx = y1@W1^T + flip(y2)@W2^T + x ----
  mmerge_k<<<gM, blk, 0, stream>>>(Q, R, o1b, o2b, x, Sf);

  // ---- LN1 (fp32 -> P, bf16 copy -> Q) ----
  ln_k<<<MROWS, blk, 0, stream>>>(Sf, ln1_g, ln1_b, Pf, Q);

  // ---- FFN, 2 chunks of 1024 over DFF ----
  mgemm_k<MEPI_BIAS_GELU, false, bf16><<<gP, blk, 0, stream>>>(
      Q, DM, c1b, DM, R, 1024, c1_b, nullptr, DM);
  mgemm_k<MEPI_BIAS_RES, false, float><<<gM, blk, 0, stream>>>(
      R, 1024, c2b, DFF, Sf, DM, c2_b, Pf, 1024);
  mgemm_k<MEPI_BIAS_GELU, false, bf16><<<gP, blk, 0, stream>>>(
      Q, DM, c1b + 1024L * DM, DM, R, 1024, c1_b + 1024, nullptr, DM);
  mgemm_k<MEPI_ACCUM_F32, false, float><<<gM, blk, 0, stream>>>(
      R, 1024, c2b + 1024, DFF, Sf, DM, nullptr, nullptr, 1024);

  // ---- LN2 -> fp32 out (overwrites xdbl/bcT scratch) ----
  ln_k<<<MROWS, blk, 0, stream>>>(Sf, ln2_g, ln2_b, (float*)d_out, nullptr);
}

// Round 12
// 937.402 us; speedup vs baseline: 3.4797x; 1.0184x over previous
//
#include <hip/hip_runtime.h>
#include <hip/hip_bf16.h>
#include <math.h>

// ---------------------------------------------------------------------------
// Problem constants
// ---------------------------------------------------------------------------
#define B_SZ 8
#define L_SZ 1024
#define DM 512          // d_model
#define DFF 2048        // d_ff
#define DIN 1024        // expand * d_model
#define DSTATE 16
#define DTRANK 32
#define MROWS (B_SZ * L_SZ)   // 8192

typedef __hip_bfloat16 bf16;
typedef unsigned short u16;
using f32x4 = __attribute__((ext_vector_type(4))) float;
using bfrag = __attribute__((ext_vector_type(8))) short;   // 8 bf16 = 4 VGPR

__device__ inline float ldf(const float* p, long i) { return p[i]; }
__device__ inline float ldf(const bf16* p, long i) {
  return __uint_as_float((unsigned)((const u16*)p)[i] << 16);
}
__device__ inline void stf(float* p, long i, float v) { p[i] = v; }
__device__ inline void stf(bf16* p, long i, float v) { p[i] = __float2bfloat16(v); }
__device__ inline float b2f(u16 x) {
  return __uint_as_float((unsigned)x << 16);
}
__device__ inline u16 f2b(float v) {
  union { bf16 h; u16 u; } c;
  c.h = __float2bfloat16(v);
  return c.u;
}

// B-element loader (4 consecutive): fp32 direct, bf16 convert.
__device__ inline float4 ld4f_bt(const float* p) { return *(const float4*)p; }
__device__ inline float4 ld4f_bt(const bf16* p) {
  ushort4 u = *(const ushort4*)p;
  float4 v;
  v.x = b2f(u.x); v.y = b2f(u.y); v.z = b2f(u.z); v.w = b2f(u.w);
  return v;
}

// 16-element row loader into packed bf16 (2 x uint4). bf16 src: direct.
// fp32 src: inline RNE convert (matches cvt path numerically).
__device__ inline void ld16(const bf16* p, uint4& lo, uint4& hi) {
  lo = *(const uint4*)p;
  hi = *(const uint4*)((const u16*)p + 8);
}
__device__ inline void ld16(const float* p, uint4& lo, uint4& hi) {
  float4 a = *(const float4*)p, b = *(const float4*)(p + 4);
  float4 c = *(const float4*)(p + 8), d = *(const float4*)(p + 12);
  union { uint4 v; u16 s[8]; } L, H;
  L.s[0] = f2b(a.x); L.s[1] = f2b(a.y); L.s[2] = f2b(a.z); L.s[3] = f2b(a.w);
  L.s[4] = f2b(b.x); L.s[5] = f2b(b.y); L.s[6] = f2b(b.z); L.s[7] = f2b(b.w);
  H.s[0] = f2b(c.x); H.s[1] = f2b(c.y); H.s[2] = f2b(c.z); H.s[3] = f2b(c.w);
  H.s[4] = f2b(d.x); H.s[5] = f2b(d.y); H.s[6] = f2b(d.z); H.s[7] = f2b(d.w);
  lo = L.v; hi = H.v;
}

// DPP rotation-butterfly add within a 16-lane row: pure VALU, no LGKM waits.
template <int CTRL>
__device__ inline float dpp_ror_add(float x) {
  int r = __builtin_amdgcn_update_dpp(0, __float_as_int(x), CTRL, 0xf, 0xf, true);
  return x + __int_as_float(r);
}
__device__ inline float row16_sum(float x) {
  x = dpp_ror_add<0x128>(x);  // row_ror:8
  x = dpp_ror_add<0x124>(x);  // row_ror:4
  x = dpp_ror_add<0x122>(x);  // row_ror:2
  x = dpp_ror_add<0x121>(x);  // row_ror:1
  return x;
}

// ---------------------------------------------------------------------------
// fp32 -> bf16 convert (weights -> d_out scratch)
// ---------------------------------------------------------------------------
__global__ __launch_bounds__(256) void cvt_k(const float* __restrict__ s,
                                             bf16* __restrict__ d, int n) {
  int i = blockIdx.x * 256 + threadIdx.x;
  if (i < n) d[i] = __float2bfloat16(s[i]);
}

// ---------------------------------------------------------------------------
// bf16 MFMA GEMM: C(M,N) = A(M,K) @ W(N,K)^T, fp32 accumulate.
// 128x128 tile, BK=32, 4 waves, each 64x64 via 4x4 v_mfma_f32_16x16x32_bf16.
// TA may be float (inline bf16 conversion in staging). W always bf16.
// ---------------------------------------------------------------------------
constexpr int MEPI_STORE_BF16 = 0;
constexpr int MEPI_GATE = 1;        // C[oi] = C[oi] * silu(acc), bf16 in-place
constexpr int MEPI_BIAS_GELU = 2;   // bf16 out
constexpr int MEPI_BIAS_RES = 3;    // fp32 out = acc + bias + res

template <int EPI, bool FLIPA, typename TA, typename TO>
__global__ __launch_bounds__(256) void mgemm_k(
    const TA* __restrict__ Ab, int lda,
    const bf16* __restrict__ Wb, int ldw,
    TO* __restrict__ C, int ldc,
    const float* __restrict__ bias,
    const float* __restrict__ res,
    int K) {
  __shared__ u16 Asm[128][40];
  __shared__ u16 Wsm[128][40];
  const int tid = threadIdx.x;
  const int m0 = blockIdx.y * 128;
  const int n0 = blockIdx.x * 128;

  const int srow = tid >> 1;
  const int scol = (tid & 1) * 16;
  int ar = m0 + srow;
  if (FLIPA) { int t = ar & (L_SZ - 1); ar = (ar - t) + (L_SZ - 1 - t); }
  const TA* Ag = Ab + (long)ar * lda + scol;
  const u16* Wg = (const u16*)Wb + (long)(n0 + srow) * ldw + scol;

  const int lane = tid & 63, quad = lane >> 4, l16 = lane & 15;
  const int wid = tid >> 6;
  const int wm = (wid & 1) * 64, wn = (wid >> 1) * 64;

  f32x4 acc[4][4];
#pragma unroll
  for (int i = 0; i < 4; ++i)
#pragma unroll
    for (int j = 0; j < 4; ++j) acc[i][j] = {0.f, 0.f, 0.f, 0.f};

  for (int k0 = 0; k0 < K; k0 += 32) {
    uint4 av0, av1, wv0, wv1;
    ld16(Ag + k0, av0, av1);
    ld16((const bf16*)(Wg + k0), wv0, wv1);
    __syncthreads();
    *(uint4*)&Asm[srow][scol] = av0;
    *(uint4*)&Asm[srow][scol + 8] = av1;
    *(uint4*)&Wsm[srow][scol] = wv0;
    *(uint4*)&Wsm[srow][scol + 8] = wv1;
    __syncthreads();
    bfrag a[4], b[4];
#pragma unroll
    for (int mi = 0; mi < 4; ++mi)
      a[mi] = *(const bfrag*)&Asm[wm + mi * 16 + l16][quad * 8];
#pragma unroll
    for (int ni = 0; ni < 4; ++ni)
      b[ni] = *(const bfrag*)&Wsm[wn + ni * 16 + l16][quad * 8];
#pragma unroll
    for (int mi = 0; mi < 4; ++mi)
#pragma unroll
      for (int ni = 0; ni < 4; ++ni)
        acc[mi][ni] = __builtin_amdgcn_mfma_f32_16x16x32_bf16(
            a[mi], b[ni], acc[mi][ni], 0, 0, 0);
  }

#pragma unroll
  for (int mi = 0; mi < 4; ++mi)
#pragma unroll
    for (int ni = 0; ni < 4; ++ni)
#pragma unroll
      for (int r = 0; r < 4; ++r) {
        int row = m0 + wm + mi * 16 + quad * 4 + r;
        int col = n0 + wn + ni * 16 + l16;
        long oi = (long)row * ldc + col;
        float v = acc[mi][ni][r];
        if (EPI == MEPI_STORE_BF16) {
          stf(C, oi, v);
        } else if (EPI == MEPI_GATE) {
          float y = ldf((const bf16*)C, oi);
          float sz = v / (1.f + __expf(-v));
          stf(C, oi, y * sz);
        } else if (EPI == MEPI_BIAS_GELU) {
          v += bias[col];
          v = 0.5f * v * (1.f + erff(v * 0.70710678118654752440f));
          stf(C, oi, v);
        } else if (EPI == MEPI_BIAS_RES) {
          ((float*)C)[oi] = v + bias[col] + res[oi];
        }
      }
}

// ---------------------------------------------------------------------------
// MFMA merge: newx(M,DM) = y1 @ W1^T + flip_L(y2) @ W2^T + xres (fp32 out).
// ---------------------------------------------------------------------------
__global__ __launch_bounds__(256) void mmerge_k(
    const bf16* __restrict__ y1, const bf16* __restrict__ y2,
    const bf16* __restrict__ W1, const bf16* __restrict__ W2,
    const float* __restrict__ xres, float* __restrict__ newx) {
  __shared__ u16 Asm[128][40];
  __shared__ u16 Wsm[128][40];
  const int tid = threadIdx.x;
  const int m0 = blockIdx.y * 128;
  const int n0 = blockIdx.x * 128;

  const int srow = tid >> 1;
  const int scol = (tid & 1) * 16;
  int r1 = m0 + srow;
  int tt = r1 & (L_SZ - 1);
  int r2 = (r1 - tt) + (L_SZ - 1 - tt);
  const u16* A1g = (const u16*)y1 + (long)r1 * DIN + scol;
  const u16* A2g = (const u16*)y2 + (long)r2 * DIN + scol;
  const u16* W1g = (const u16*)W1 + (long)(n0 + srow) * DIN + scol;
  const u16* W2g = (const u16*)W2 + (long)(n0 + srow) * DIN + scol;

  const int lane = tid & 63, quad = lane >> 4, l16 = lane & 15;
  const int wid = tid >> 6;
  const int wm = (wid & 1) * 64, wn = (wid >> 1) * 64;

  f32x4 acc[4][4];
#pragma unroll
  for (int i = 0; i < 4; ++i)
#pragma unroll
    for (int j = 0; j < 4; ++j) acc[i][j] = {0.f, 0.f, 0.f, 0.f};

  for (int k0 = 0; k0 < 2 * DIN; k0 += 32) {
    const bool ph2 = (k0 >= DIN);
    const int kk = k0 & (DIN - 1);
    const u16* Ag = ph2 ? A2g : A1g;
    const u16* Wg = ph2 ? W2g : W1g;
    uint4 av0 = *(const uint4*)(Ag + kk);
    uint4 av1 = *(const uint4*)(Ag + kk + 8);
    uint4 wv0 = *(const uint4*)(Wg + kk);
    uint4 wv1 = *(const uint4*)(Wg + kk + 8);
    __syncthreads();
    *(uint4*)&Asm[srow][scol] = av0;
    *(uint4*)&Asm[srow][scol + 8] = av1;
    *(uint4*)&Wsm[srow][scol] = wv0;
    *(uint4*)&Wsm[srow][scol + 8] = wv1;
    __syncthreads();
    bfrag a[4], b[4];
#pragma unroll
    for (int mi = 0; mi < 4; ++mi)
      a[mi] = *(const bfrag*)&Asm[wm + mi * 16 + l16][quad * 8];
#pragma unroll
    for (int ni = 0; ni < 4; ++ni)
      b[ni] = *(const bfrag*)&Wsm[wn + ni * 16 + l16][quad * 8];
#pragma unroll
    for (int mi = 0; mi < 4; ++mi)
#pragma unroll
      for (int ni = 0; ni < 4; ++ni)
        acc[mi][ni] = __builtin_amdgcn_mfma_f32_16x16x32_bf16(
            a[mi], b[ni], acc[mi][ni], 0, 0, 0);
  }

#pragma unroll
  for (int mi = 0; mi < 4; ++mi)
#pragma unroll
    for (int ni = 0; ni < 4; ++ni)
#pragma unroll
      for (int r = 0; r < 4; ++r) {
        int row = m0 + wm + mi * 16 + quad * 4 + r;
        int col = n0 + wn + ni * 16 + l16;
        long oi = (long)row * DM + col;
        newx[oi] = acc[mi][ni][r] + xres[oi];
      }
}

// ---------------------------------------------------------------------------
// Vector-ALU GEMM with ROW-MAJOR B: C(M,N) = A(M,K) @ B(K,N).
//   EPI_NONE:          fp32 out (xdblT: A=xp_w 64x1024, B=xcT -> 64x8192)
//   EPI_SOFTPLUS_ROW:  softplus(acc + bias[row]) bf16 out
//                      (dtT: A=dtp_w 1024x32, B=xdblT rows 0..31 -> 1024x8192)
// ---------------------------------------------------------------------------
constexpr int EPI_NONE = 0;
constexpr int EPI_SOFTPLUS_ROW = 1;

#define BM 64
#define BN 64
#define BKK 16

template <int EPI, typename TB, typename TO>
__global__ __launch_bounds__(256) void gemmBT_k(
    const float* __restrict__ A,
    const TB* __restrict__ B,
    TO* __restrict__ C, int N,
    const float* __restrict__ bias, int K) {
  __shared__ float As[BKK][BM + 4];
  __shared__ float Bs[BKK][BN + 4];
  const int tid = threadIdx.x;
  const int m0 = blockIdx.y * BM;
  const int n0 = blockIdx.x * BN;
  const int tx = tid & 15;
  const int ty = tid >> 4;
  const int lrow = tid >> 2;        // A-stage: m index 0..63
  const int lcol = (tid & 3) * 4;   // A-stage: k offset 0,4,8,12
  const int kr = tid >> 4;          // B-stage: k index 0..15
  const int nc = (tid & 15) * 4;    // B-stage: n offset

  const float* Arow = A + (long)(m0 + lrow) * K;

  float acc[4][4] = {};
  for (int k0 = 0; k0 < K; k0 += BKK) {
    float4 av = *(const float4*)(Arow + k0 + lcol);
    float4 bv = ld4f_bt(B + (long)(k0 + kr) * N + n0 + nc);
    As[lcol + 0][lrow] = av.x; As[lcol + 1][lrow] = av.y;
    As[lcol + 2][lrow] = av.z; As[lcol + 3][lrow] = av.w;
    Bs[kr][nc + 0] = bv.x; Bs[kr][nc + 1] = bv.y;
    Bs[kr][nc + 2] = bv.z; Bs[kr][nc + 3] = bv.w;
    __syncthreads();
#pragma unroll
    for (int k = 0; k < BKK; ++k) {
      float a[4], b[4];
#pragma unroll
      for (int i = 0; i < 4; ++i) a[i] = As[k][ty * 4 + i];
#pragma unroll
      for (int j = 0; j < 4; ++j) b[j] = Bs[k][tx * 4 + j];
#pragma unroll
      for (int i = 0; i < 4; ++i)
#pragma unroll
        for (int j = 0; j < 4; ++j) acc[i][j] += a[i] * b[j];
    }
    __syncthreads();
  }

#pragma unroll
  for (int i = 0; i < 4; ++i) {
    int r = m0 + ty * 4 + i;
#pragma unroll
    for (int j = 0; j < 4; ++j) {
      int c = n0 + tx * 4 + j;
      float v = acc[i][j];
      if (EPI == EPI_SOFTPLUS_ROW) {
        v += bias[r];
        v = (v > 20.f) ? v : log1pf(__expf(v));
      }
      stf(C, (long)r * N + c, v);
    }
  }
}

// ---------------------------------------------------------------------------
// Fused depthwise causal conv (k=4) + bias + silu + TRANSPOSE.
// in  xs: (MROWS x DIN) bf16  ->  out xcT: (DIN x MROWS) bf16.
// 64x64 tiles; 3-column halo for the causal window; halo zeroed at batch head.
// ---------------------------------------------------------------------------
__global__ __launch_bounds__(256) void convT_k(
    const bf16* __restrict__ xs, const float* __restrict__ w,
    const float* __restrict__ b, bf16* __restrict__ xcT) {
  __shared__ u16 T[64][72];   // [d_local][bt_local + 3 halo]
  int c0 = blockIdx.x * 64;   // d
  int r0 = blockIdx.y * 64;   // bt
  int tid = threadIdx.x;
  int tr = tid >> 2;          // 0..63
  int tc = (tid & 3) * 16;    // 0,16,32,48

  // main tile: row r0+tr, cols c0+tc..+15 -> T[tc+j][tr+3]
  const u16* src = (const u16*)xs + (long)(r0 + tr) * DIN + c0 + tc;
  uint4 v0 = *(const uint4*)src;
  uint4 v1 = *(const uint4*)(src + 8);
  u16 tmp[16];
  *(uint4*)tmp = v0;
  *(uint4*)(tmp + 8) = v1;
#pragma unroll
  for (int j = 0; j < 16; ++j) T[tc + j][tr + 3] = tmp[j];
  // halo: rows r0-3..r0-1 (zero at batch head), threads 0..11
  bool head = (r0 & (L_SZ - 1)) == 0;
  if (tid < 12) {
    int hr = tid >> 2;            // 0..2
    int seg = (tid & 3) * 16;
    if (head) {
#pragma unroll
      for (int j = 0; j < 16; ++j) T[seg + j][hr] = 0;
    } else {
      const u16* hs = (const u16*)xs + (long)(r0 - 3 + hr) * DIN + c0 + seg;
      uint4 h0 = *(const uint4*)hs;
      uint4 h1 = *(const uint4*)(hs + 8);
      u16 ht[16];
      *(uint4*)ht = h0;
      *(uint4*)(ht + 8) = h1;
#pragma unroll
      for (int j = 0; j < 16; ++j) T[seg + j][hr] = ht[j];
    }
  }
  __syncthreads();

  // compute: thread -> d_local = tr, bt_local base = tc
  int d = c0 + tr;
  float w0 = w[d * 4 + 0], w1 = w[d * 4 + 1], w2 = w[d * 4 + 2], w3 = w[d * 4 + 3];
  float bd = b[d];
  float X[19];
#pragma unroll
  for (int k = 0; k < 19; ++k) X[k] = b2f(T[tr][tc + k]);
  u16 o[16];
#pragma unroll
  for (int j = 0; j < 16; ++j) {
    float acc = bd + w0 * X[j] + w1 * X[j + 1] + w2 * X[j + 2] + w3 * X[j + 3];
    o[j] = f2b(acc / (1.f + __expf(-acc)));
  }
  u16* dst = (u16*)xcT + (long)d * MROWS + r0 + tc;
  *(uint4*)dst = *(uint4*)o;
  *(uint4*)(dst + 8) = *(uint4*)(o + 8);
}

// ---------------------------------------------------------------------------
// Merged bidirectional selective scan + skip (u*D). 1024 blocks:
// blocks [0,512) = dir1, [512,1024) = dir2 (4 waves/SIMD occupancy).
// dtT,uT: (DIN x MROWS) bf16 t-contiguous; B/C from xdblT rows 32..63 fp32.
// Output y UNGATED, normal (bt,d) layout bf16 (gating in mgemm epilogue).
// Depth-2 vector prefetch; 16-lane DPP reduce.
// ---------------------------------------------------------------------------
__global__ __launch_bounds__(256) void scan_k(
    const u16* __restrict__ dtT1, const u16* __restrict__ dtT2,
    const u16* __restrict__ uT1, const u16* __restrict__ uT2,
    const float* __restrict__ xd1, const float* __restrict__ xd2,
    const float* __restrict__ Alog1, const float* __restrict__ Alog2,
    const float* __restrict__ D1, const float* __restrict__ D2,
    bf16* __restrict__ y1, bf16* __restrict__ y2) {
  int blk = blockIdx.x;
  int dir = blk >> 9;
  int idx = blk & 511;
  int tid = threadIdx.x;
  int s = tid & 15;
  int gi = tid >> 4;
  int b = idx >> 6;
  int d = ((idx & 63) << 4) + gi;
  const u16* dtT = dir ? dtT2 : dtT1;
  const u16* uT = dir ? uT2 : uT1;
  const float* xd = dir ? xd2 : xd1;
  const float* Alog = dir ? Alog2 : Alog1;
  const float* Dp = dir ? D2 : D1;
  bf16* out = dir ? y2 : y1;

  float A = -__expf(Alog[d * DSTATE + s]);
  float Dd = Dp[d];
  float h = 0.f;
  const u16* pdt = dtT + (long)d * MROWS + b * L_SZ;
  const u16* pu = uT + (long)d * MROWS + b * L_SZ;
  const float* pB = xd + (long)(DTRANK + s) * MROWS + b * L_SZ;
  const float* pC = xd + (long)(DTRANK + DSTATE + s) * MROWS + b * L_SZ;
  long io = (long)b * L_SZ * DIN + d;

  union F8 { float4 v[2]; float a[8]; };
  union U8 { uint4 v; u16 a[8]; };
  uint4 dt0 = *(const uint4*)pdt, dt1 = *(const uint4*)(pdt + 8);
  uint4 u0 = *(const uint4*)pu, u1 = *(const uint4*)(pu + 8);
  F8 B0, B1, C0, C1;
  B0.v[0] = *(const float4*)pB; B0.v[1] = *(const float4*)(pB + 4);
  B1.v[0] = *(const float4*)(pB + 8); B1.v[1] = *(const float4*)(pB + 12);
  C0.v[0] = *(const float4*)pC; C0.v[1] = *(const float4*)(pC + 4);
  C1.v[0] = *(const float4*)(pC + 8); C1.v[1] = *(const float4*)(pC + 12);

  for (int g = 0; g < L_SZ / 8; ++g) {
    U8 cdt, cu;
    F8 cB, cC;
    cdt.v = dt0; cu.v = u0; cB = B0; cC = C0;
    dt0 = dt1; u0 = u1; B0 = B1; C0 = C1;
    if (g + 2 < L_SZ / 8) {
      int off = (g + 2) * 8;
      dt1 = *(const uint4*)(pdt + off);
      u1 = *(const uint4*)(pu + off);
      B1.v[0] = *(const float4*)(pB + off); B1.v[1] = *(const float4*)(pB + off + 4);
      C1.v[0] = *(const float4*)(pC + off); C1.v[1] = *(const float4*)(pC + off + 4);
    }
#pragma unroll
    for (int j = 0; j < 8; ++j) {
      float dtv = b2f(cdt.a[j]);
      float uv = b2f(cu.a[j]);
      float da = __expf(dtv * A);
      h = da * h + (dtv * uv) * cB.a[j];
      float p = row16_sum(h * cC.a[j]);
      if (s == 0) stf(out, io + (long)j * DIN, p + Dd * uv);
    }
    io += 8L * DIN;
  }
}

// ---------------------------------------------------------------------------
// LayerNorm over last dim (512). fp32 in; fp32 out + optional bf16 copy.
// Safe in-place (all reads precede all writes per thread; one block per row).
// ---------------------------------------------------------------------------
__global__ __launch_bounds__(256) void ln_k(
    const float* __restrict__ xin, const float* __restrict__ g,
    const float* __restrict__ bb, float* __restrict__ out,
    bf16* __restrict__ outb) {
  int row = blockIdx.x;
  const float* p = xin + (long)row * DM;
  int tid = threadIdx.x;
  float x0 = p[tid], x1 = p[tid + 256];
  float sum = x0 + x1;
  float sq = x0 * x0 + x1 * x1;
#pragma unroll
  for (int o = 1; o < 64; o <<= 1) {
    sum += __shfl_xor(sum, o, 64);
    sq += __shfl_xor(sq, o, 64);
  }
  __shared__ float ssum[4], ssq[4];
  int wv = tid >> 6;
  if ((tid & 63) == 0) { ssum[wv] = sum; ssq[wv] = sq; }
  __syncthreads();
  sum = ssum[0] + ssum[1] + ssum[2] + ssum[3];
  sq = ssq[0] + ssq[1] + ssq[2] + ssq[3];
  float mean = sum * (1.f / DM);
  float var = sq * (1.f / DM) - mean * mean;
  float rstd = rsqrtf(var + 1e-5f);
  float v0 = (x0 - mean) * rstd * g[tid] + bb[tid];
  float v1 = (x1 - mean) * rstd * g[tid + 256] + bb[tid + 256];
  out[(long)row * DM + tid] = v0;
  out[(long)row * DM + tid + 256] = v1;
  if (outb) {
    stf(outb, (long)row * DM + tid, v0);
    stf(outb, (long)row * DM + tid + 256, v1);
  }
}

// ---------------------------------------------------------------------------
// Orchestration. Workspace: 6 slots x 16 MB = 96 MB (proven safe at R4):
//  A[0,16):  xs1 -> y1 -> gated y1 -> outacc(fp32)
//  B[16,32): xcT1 (=uT1, live thru scan) -> xln fp32
//  C[32,48): dtT1 (live thru scan) -> newx fp32 -> ffn head (32 MB span C+D)
//  D[48,64): xs2 -> y2 -> gated y2 -> ffn tail
//  E[64,80): xcT2 (=uT2) -> xln bf16
//  F[80,96): dtT2
// d_out (16 MB): bf16 weights [0,10 MB) + xdblT1 @10MB + xdblT2 @12MB (fp32);
//               all dead before FFN-down; LN2 overwrites d_out at the end.
// x and in-proj/gate A-operands convert fp32->bf16 inline in mgemm staging.
// ---------------------------------------------------------------------------
extern "C" void kernel_launch(void* const* d_in, const int* in_sizes, int n_in,
                              void* d_out, int out_size, void* d_ws, size_t ws_size,
                              hipStream_t stream) {
  const float* x = (const float*)d_in[0];
  const float* in1_w = (const float*)d_in[1];
  const float* conv1_w = (const float*)d_in[2];
  const float* conv1_b = (const float*)d_in[3];
  const float* xp1_w = (const float*)d_in[4];
  const float* dtp1_w = (const float*)d_in[5];
  const float* dtp1_b = (const float*)d_in[6];
  const float* Alog1 = (const float*)d_in[7];
  const float* D1 = (const float*)d_in[8];
  const float* outp1_w = (const float*)d_in[9];
  const float* in2_w = (const float*)d_in[10];
  const float* conv2_w = (const float*)d_in[11];
  const float* conv2_b = (const float*)d_in[12];
  const float* xp2_w = (const float*)d_in[13];
  const float* dtp2_w = (const float*)d_in[14];
  const float* dtp2_b = (const float*)d_in[15];
  const float* Alog2 = (const float*)d_in[16];
  const float* D2 = (const float*)d_in[17];
  const float* outp2_w = (const float*)d_in[18];
  const float* c1_w = (const float*)d_in[19];
  const float* c1_b = (const float*)d_in[20];
  const float* c2_w = (const float*)d_in[21];
  const float* c2_b = (const float*)d_in[22];
  const float* ln1_g = (const float*)d_in[23];
  const float* ln1_b = (const float*)d_in[24];
  const float* ln2_g = (const float*)d_in[25];
  const float* ln2_b = (const float*)d_in[26];

  const long MB = 1024L * 1024;
  char* wsb = (char*)d_ws;
  bf16* A = (bf16*)(wsb + 0 * MB);
  bf16* B = (bf16*)(wsb + 16 * MB);
  bf16* C = (bf16*)(wsb + 32 * MB);
  bf16* D = (bf16*)(wsb + 48 * MB);
  bf16* E = (bf16*)(wsb + 64 * MB);
  bf16* F = (bf16*)(wsb + 80 * MB);
  float* Bf = (float*)B;   // xln fp32
  float* Cf = (float*)C;   // newx fp32
  float* Af = (float*)A;   // outacc fp32
  bf16* ffn = C;           // 32 MB span C+D, ldc = 2048

  char* ob = (char*)d_out;
  bf16* in1b = (bf16*)(ob + 0 * MB);   // 1M elems (2 MB)
  bf16* in2b = (bf16*)(ob + 2 * MB);
  bf16* o1b = (bf16*)(ob + 4 * MB);    // 512K (1 MB)
  bf16* o2b = (bf16*)(ob + 5 * MB);
  bf16* c1b = (bf16*)(ob + 6 * MB);    // 1M (2 MB)
  bf16* c2b = (bf16*)(ob + 8 * MB);
  float* xdT1 = (float*)(ob + 10 * MB);  // 64x8192 fp32 (2 MB)
  float* xdT2 = (float*)(ob + 12 * MB);

  dim3 blk(256);
  dim3 gP(DIN / 128, MROWS / 128);      // N=1024 MFMA
  dim3 gM(DM / 128, MROWS / 128);       // N=512 MFMA
  dim3 gF(DFF / 128, MROWS / 128);      // N=2048 MFMA
  dim3 gC(DIN / 64, MROWS / 64);        // convT tiles
  dim3 gX(MROWS / BN, 64 / BM);         // xdblT: M=64
  dim3 gD(MROWS / BN, DIN / BM);        // dtT: M=1024

  // ---- weight conversions into d_out ----
  cvt_k<<<(2 * DIN * DM) / 256, blk, 0, stream>>>(in1_w, in1b, 2 * DIN * DM);
  cvt_k<<<(2 * DIN * DM) / 256, blk, 0, stream>>>(in2_w, in2b, 2 * DIN * DM);
  cvt_k<<<(DM * DIN) / 256, blk, 0, stream>>>(outp1_w, o1b, DM * DIN);
  cvt_k<<<(DM * DIN) / 256, blk, 0, stream>>>(outp2_w, o2b, DM * DIN);
  cvt_k<<<(DFF * DM) / 256, blk, 0, stream>>>(c1_w, c1b, DFF * DM);
  cvt_k<<<(DM * DFF) / 256, blk, 0, stream>>>(c2_w, c2b, DM * DFF);

  // ---- direction 1 prelude ----
  mgemm_k<MEPI_STORE_BF16, false, float, bf16><<<gP, blk, 0, stream>>>(
      x, DM, in1b, DM, A, DIN, nullptr, nullptr, DM);                    // xs1
  convT_k<<<gC, blk, 0, stream>>>(A, conv1_w, conv1_b, B);               // xcT1
  gemmBT_k<EPI_NONE, bf16, float><<<gX, blk, 0, stream>>>(
      xp1_w, B, xdT1, MROWS, nullptr, DIN);                              // xdblT1
  gemmBT_k<EPI_SOFTPLUS_ROW, float, bf16><<<gD, blk, 0, stream>>>(
      dtp1_w, xdT1, C, MROWS, dtp1_b, DTRANK);                           // dtT1

  // ---- direction 2 prelude ----
  mgemm_k<MEPI_STORE_BF16, true, float, bf16><<<gP, blk, 0, stream>>>(
      x, DM, in2b, DM, D, DIN, nullptr, nullptr, DM);                    // xs2
  convT_k<<<gC, blk, 0, stream>>>(D, conv2_w, conv2_b, E);               // xcT2
  gemmBT_k<EPI_NONE, bf16, float><<<gX, blk, 0, stream>>>(
      xp2_w, E, xdT2, MROWS, nullptr, DIN);                              // xdblT2
  gemmBT_k<EPI_SOFTPLUS_ROW, float, bf16><<<gD, blk, 0, stream>>>(
      dtp2_w, xdT2, F, MROWS, dtp2_b, DTRANK);                           // dtT2

  // ---- merged bidirectional scan: y1 -> A, y2 -> D ----
  scan_k<<<2 * B_SZ * (DIN / 16), blk, 0, stream>>>(
      (const u16*)C, (const u16*)F, (const u16*)B, (const u16*)E,
      xdT1, xdT2, Alog1, Alog2, D1, D2, A, D);

  // ---- gates (in-place over y) ----
  mgemm_k<MEPI_GATE, false, float, bf16><<<gP, blk, 0, stream>>>(
      x, DM, in1b + (long)DIN * DM, DM, A, DIN, nullptr, nullptr, DM);
  mgemm_k<MEPI_GATE, true, float, bf16><<<gP, blk, 0, stream>>>(
      x, DM, in2b + (long)DIN * DM, DM, D, DIN, nullptr, nullptr, DM);

  // ---- merge: newx = y1@W1^T + flip(y2)@W2^T + x -> C (fp32) ----
  mmerge_k<<<gM, blk, 0, stream>>>(A, D, o1b, o2b, x, Cf);

  // ---- LN1: fp32 -> B, bf16 -> E ----
  ln_k<<<MROWS, blk, 0, stream>>>(Cf, ln1_g, ln1_b, Bf, E);

  // ---- FFN (single up, single down) ----
  mgemm_k<MEPI_BIAS_GELU, false, bf16, bf16><<<gF, blk, 0, stream>>>(
      E, DM, c1b, DM, ffn, DFF, c1_b, nullptr, DM);
  mgemm_k<MEPI_BIAS_RES, false, bf16, float><<<gM, blk, 0, stream>>>(
      ffn, DFF, c2b, DFF, Af, DM, c2_b, Bf, DFF);

  // ---- LN2 -> d_out (weights/xdblT scratch dead) ----
  ln_k<<<MROWS, blk, 0, stream>>>(Af, ln2_g, ln2_b, (float*)d_out, nullptr);
}